// Round 8
// baseline (102.372 us; speedup 1.0000x reference)
//
#include <hip/hip_runtime.h>
#include <cstdint>

// HebbFF T=128,B=8,N=512,D=256,O=1. Gram-matrix reformulation:
//   z(t) = w_add@h_m(t) + b_add + sum_{s<t} W[t][s] u(s),  u = sigmoid(z)
//   W[t][s] = eta_a * lam_a^(t-1-s) * (h_m(s).h_m(t))
// R8: 32-lane split-K everywhere.
//   np_part1: h_mult chain, halves of each wave own 2 rows (5-DPP reduce,
//             one tanh), x fully LDS-staged; emits h_pair[t2*8+b][n][2].
//   np_mid:   base GEMM on 2048 blocks (1 hp row x 128 n each): float4
//             coalesced w loads + prefetch, 32-lane pair reduce. gram on
//             128 blocks (R7 + prefetch). No bias here.
//   np_scan:  W_b in LDS; 16-tiles: parallel history FMA + wave0 triangle;
//             b_add folded in at load.
//   np_final: y = sigmoid(w_final.u + b_final).
// ws (floats): hp@0 (524288) | z0/u@524288 (524288) | W@1048576 (131072).
// Fallback to R5 path if ws too small.

#define T_ 128
#define B_ 8
#define N_ 512
#define D_ 256
#define HP_OFF 0
#define Z0_OFF 524288
#define WS_OFF 1048576
#define WS_NEED ((size_t)(1048576 + 131072) * 4)
#define HOFF (T_ * B_ * N_)   // fallback layout
#define CH 16
#define NC (T_ / CH)

typedef float v2f __attribute__((ext_vector_type(2)));

__device__ __forceinline__ v2f v2(float s) { v2f r; r.x = s; r.y = s; return r; }
__device__ __forceinline__ v2f mk2(float a, float b) { v2f r; r.x = a; r.y = b; return r; }

__device__ __forceinline__ void load_lds16(const float* g, float* l) {
  __builtin_amdgcn_global_load_lds(
      (const __attribute__((address_space(1))) uint32_t*)(const void*)g,
      (__attribute__((address_space(3))) uint32_t*)(void*)l, 16, 0, 0);
}

#define DPP1(v, ctrl)                                                          \
  v += __int_as_float(                                                         \
      __builtin_amdgcn_update_dpp(0, __float_as_int(v), ctrl, 0xf, 0xf, true))

// 64-lane sum, total in lane 63
__device__ __forceinline__ float dpp_red(float v) {
  DPP1(v, 0x111); DPP1(v, 0x112); DPP1(v, 0x114); DPP1(v, 0x118);
  DPP1(v, 0x142); DPP1(v, 0x143);
  return v;
}
// 64-lane pair sum, totals in lane 63
__device__ __forceinline__ v2f dpp_red2(v2f v) {
  float a = v.x, b = v.y;
  DPP1(a, 0x111); DPP1(b, 0x111); DPP1(a, 0x112); DPP1(b, 0x112);
  DPP1(a, 0x114); DPP1(b, 0x114); DPP1(a, 0x118); DPP1(b, 0x118);
  DPP1(a, 0x142); DPP1(b, 0x142); DPP1(a, 0x143); DPP1(b, 0x143);
  v.x = a; v.y = b;
  return v;
}
// 32-lane sum: lane31 = sum(lanes 0..31), lane63 = sum(lanes 32..63)
__device__ __forceinline__ float dpp_red1_32(float v) {
  DPP1(v, 0x111); DPP1(v, 0x112); DPP1(v, 0x114); DPP1(v, 0x118);
  DPP1(v, 0x142);
  return v;
}
__device__ __forceinline__ v2f dpp_red2_32(v2f v) {
  float a = v.x, b = v.y;
  DPP1(a, 0x111); DPP1(b, 0x111); DPP1(a, 0x112); DPP1(b, 0x112);
  DPP1(a, 0x114); DPP1(b, 0x114); DPP1(a, 0x118); DPP1(b, 0x118);
  DPP1(a, 0x142); DPP1(b, 0x142);
  v.x = a; v.y = b;
  return v;
}
// broadcast total to all lanes
__device__ __forceinline__ float dpp_wave_sum(float v) {
  v = dpp_red(v);
  return __int_as_float(__builtin_amdgcn_readlane(__float_as_int(v), 63));
}
__device__ __forceinline__ float sigmoid_f(float z) {
  return __builtin_amdgcn_rcpf(1.f + __expf(-z));
}
__device__ __forceinline__ float tanh_f(float z) {
  return 1.f - 2.f * __builtin_amdgcn_rcpf(1.f + __expf(2.f * z));
}

// ---------------- np_part1: h_mult / A_mult chain (32-lane split) ----------
// 256 blocks (g, sub) x 8 waves; each wave owns rows n0 (half0) / n0+1
// (half1). k = 2*(lane&31) + 64c. Bm = A_mult + 1.
__global__ void __launch_bounds__(512, 1)
np_part1(const float* __restrict__ x, const float* __restrict__ w_mult,
         const float* __restrict__ b_mult, const float* __restrict__ p_lm,
         const float* __restrict__ p_em, float* __restrict__ ws) {
  const int g = blockIdx.x & 7, sub = blockIdx.x >> 3;
  const int wave = threadIdx.x >> 6, lane = threadIdx.x & 63;
  const int l31 = lane & 31, half = lane >> 5;
  const int n0 = (sub * 8 + wave) * 2;
  const int n = n0 + half;

  __shared__ float xs[T_][D_];  // 128 KB: ALL x rows for batch g
#pragma unroll
  for (int i = 0; i < 16; ++i) {
    const int r = wave * 16 + i;
    load_lds16(&x[(r * B_ + g) * D_ + 4 * lane], &xs[r][0]);
  }

  const float lam = sigmoid_f(p_lm[0]);
  const float eta = p_em[0];
  const v2f lam2 = v2(lam), klam2 = v2(1.f - lam);

  v2f wm[4], Bm[4];
#pragma unroll
  for (int c = 0; c < 4; ++c) {
    wm[c] = *(const v2f*)&w_mult[n * D_ + 64 * c + 2 * l31];
    Bm[c] = v2(1.f);
  }
  const float bm = b_mult[n];
  __syncthreads();  // x staged (drains vmcnt)

  float* hp = ws + HP_OFF;
  v2f xv[4][4];  // 4-slot ring, 3-ahead prefetch
#define LDX(slot, t)                                                           \
  {                                                                            \
    _Pragma("unroll") for (int c = 0; c < 4; ++c)                              \
        xv[slot][c] = *(const v2f*)&xs[t][64 * c + 2 * l31];                   \
  }
  LDX(0, 0) LDX(1, 1) LDX(2, 2)

  float ph = 0.f;
  for (int t4 = 0; t4 < T_; t4 += 4) {
#pragma unroll
    for (int j = 0; j < 4; ++j) {
      const int t = t4 + j;
      if (t + 3 < T_) LDX((j + 3) & 3, t + 3)
      v2f wx = wm[0] * xv[j][0];
      v2f a = wx * Bm[0];
#pragma unroll
      for (int c = 1; c < 4; ++c) {
        wx = wm[c] * xv[j][c];
        a = __builtin_elementwise_fma(wx, Bm[c], a);
      }
      float s = dpp_red1_32(a.x + a.y);
      const float zr0 =
          __int_as_float(__builtin_amdgcn_readlane(__float_as_int(s), 31));
      const float zr1 =
          __int_as_float(__builtin_amdgcn_readlane(__float_as_int(s), 63));
      const float zz = (half ? zr1 : zr0) + bm;
      const float hm = tanh_f(zz);
      const v2f c2 = v2(eta * hm);
#pragma unroll
      for (int c = 0; c < 4; ++c) {
        v2f inner = __builtin_elementwise_fma(c2, xv[j][c], klam2);
        Bm[c] = __builtin_elementwise_fma(lam2, Bm[c], inner);
      }
      if (j & 1) {  // odd t: store (h_even, h_odd) pair for this n
        if (l31 == 31)
          *(v2f*)(hp + (size_t)((t >> 1) * B_ + g) * (N_ * 2) + n * 2) =
              mk2(ph, hm);
      } else {
        ph = hm;
      }
    }
  }
#undef LDX
}

// ---------------- np_mid: base GEMM + Gram ----------------
// blocks [0,2048): base, 1 hp row x 128 n; blocks [2048,2176): gram.
__global__ void __launch_bounds__(256)
np_mid(const float* __restrict__ w_add, const float* __restrict__ p_la,
       const float* __restrict__ p_ea, float* __restrict__ ws) {
  __shared__ float hl[4096];  // 16 KB (gram: 4 rows; base: 1 row)
  const int wave = threadIdx.x >> 6, lane = threadIdx.x & 63;
  const float* hp = ws + HP_OFF;
  float* z0 = ws + Z0_OFF;
  float* Wsc = ws + WS_OFF;

  if (blockIdx.x < 2048) {
    // ---- base: z0 = h @ w_add^T (bias folded into scan) ----
    const int pr = blockIdx.x >> 2;   // hp row = t2*8 + b
    const int nq = blockIdx.x & 3;
    load_lds16(&hp[pr * 1024 + wave * 256 + 4 * lane], &hl[wave * 256]);
    __syncthreads();
    const int l31 = lane & 31, half = lane >> 5;
    // h fragment: k = 4*l31 + kk + 128*jj ; pairs at hl[2k..2k+1]
    float4 hfa[4], hfb[4];
#pragma unroll
    for (int jj = 0; jj < 4; ++jj) {
      hfa[jj] = *(const float4*)&hl[256 * jj + 8 * l31];      // kk=0,1
      hfb[jj] = *(const float4*)&hl[256 * jj + 8 * l31 + 4];  // kk=2,3
    }
    const int rowe = 16 * (pr >> 3) + (pr & 7);
    const int nbase = nq * 128 + wave * 32;
    float4 wc[4], wn[4];
    auto loadw = [&](float4* dst, int n_) {
      const float* wr = w_add + (size_t)n_ * N_ + 4 * l31;
#pragma unroll
      for (int jj = 0; jj < 4; ++jj) dst[jj] = *(const float4*)&wr[128 * jj];
    };
    loadw(wc, nbase + half);
    for (int i = 0; i < 16; ++i) {
      if (i + 1 < 16) loadw(wn, nbase + 2 * (i + 1) + half);
      v2f a = v2(0.f);
#pragma unroll
      for (int jj = 0; jj < 4; ++jj) {
        a = __builtin_elementwise_fma(mk2(hfa[jj].x, hfa[jj].y), v2(wc[jj].x), a);
        a = __builtin_elementwise_fma(mk2(hfa[jj].z, hfa[jj].w), v2(wc[jj].y), a);
        a = __builtin_elementwise_fma(mk2(hfb[jj].x, hfb[jj].y), v2(wc[jj].z), a);
        a = __builtin_elementwise_fma(mk2(hfb[jj].z, hfb[jj].w), v2(wc[jj].w), a);
      }
      a = dpp_red2_32(a);  // lane31: n(half0), lane63: n(half1)
      if (l31 == 31) {
        const int n_ = nbase + 2 * i + half;
        z0[rowe * N_ + n_] = a.x;
        z0[(rowe + 8) * N_ + n_] = a.y;
      }
#pragma unroll
      for (int jj = 0; jj < 4; ++jj) wc[jj] = wn[jj];
    }
  } else {
    // ---- gram: block (b, q): t rows [8q, 8q+8) vs s < t ----
    const int bi2 = blockIdx.x - 2048;
    const int b = bi2 & 7, q = bi2 >> 3;
    const float lam = sigmoid_f(p_la[0]);
    const float eta = p_ea[0];
#pragma unroll
    for (int i = 0; i < 4; ++i)
      load_lds16(&hp[((q * 4 + wave) * 8 + b) * 1024 + i * 256 + 4 * lane],
                 &hl[wave * 1024 + i * 256]);
    __syncthreads();
    v2f hv[4][8];
#pragma unroll
    for (int i = 0; i < 4; ++i)
#pragma unroll
      for (int j = 0; j < 8; ++j)
        hv[i][j] = ((const v2f*)hl)[i * 512 + lane + 64 * j];

    const float l2lam = __log2f(lam);
    const int tlim = q * 8 + 7;
    float wv[8], wvn[8];
    auto loadg = [&](float* dst, int tp) {
      const float* hrow = hp + ((tp >> 1) * 8 + b) * 1024 + (tp & 1);
#pragma unroll
      for (int j = 0; j < 8; ++j) dst[j] = hrow[2 * (lane + 64 * j)];
    };
    if (wave < tlim) loadg(wv, wave);
    for (int tp = wave; tp < tlim; tp += 4) {
      if (tp + 4 < tlim) loadg(wvn, tp + 4);
#pragma unroll
      for (int i = 0; i < 4; ++i) {
        v2f a = hv[i][0] * v2(wv[0]);
#pragma unroll
        for (int j = 1; j < 8; ++j)
          a = __builtin_elementwise_fma(hv[i][j], v2(wv[j]), a);
        a = dpp_red2(a);
        if (lane == 63) {
          const int te = q * 8 + 2 * i;
          if (tp < te)
            Wsc[(b * T_ + te) * T_ + tp] =
                eta * exp2f(l2lam * (float)(te - 1 - tp)) * a.x;
          if (tp < te + 1)
            Wsc[(b * T_ + te + 1) * T_ + tp] =
                eta * exp2f(l2lam * (float)(te - tp)) * a.y;
        }
      }
#pragma unroll
      for (int j = 0; j < 8; ++j) wv[j] = wvn[j];
    }
  }
}

// ---------------- np_scan: sequential sigmoid scan ----------------
__global__ void __launch_bounds__(512, 1)
np_scan(const float* __restrict__ b_add, float* __restrict__ ws) {
  __shared__ float Wl[T_][T_];   // 64 KB
  __shared__ float ul[T_][64];   // 32 KB
  __shared__ float zx[16][64];   // 4 KB
  const int b = blockIdx.x >> 3, nc = blockIdx.x & 7;
  const int wave = threadIdx.x >> 6, lane = threadIdx.x & 63;
  float* z0 = ws + Z0_OFF;
  const float* Wb = ws + WS_OFF + b * T_ * T_;

#pragma unroll
  for (int i = 0; i < 8; ++i) {
    const int r2 = wave * 16 + i * 2;
    load_lds16(&Wb[r2 * T_ + 4 * lane], &Wl[r2][0]);
  }

  const int ta = 2 * wave, tb2 = 2 * wave + 1;
  const int ncol = nc * 64 + lane;
  const float ban = b_add[ncol];

  float za = z0[(ta * B_ + b) * N_ + ncol] + ban;
  float zb = z0[(tb2 * B_ + b) * N_ + ncol] + ban;
  __syncthreads();  // W staged

  for (int j = 0; j < 8; ++j) {
    const int t0 = j * 16;
    float zna = 0.f, znb = 0.f;
    if (j < 7) {
      zna = z0[((t0 + 16 + ta) * B_ + b) * N_ + ncol] + ban;
      znb = z0[((t0 + 16 + tb2) * B_ + b) * N_ + ncol] + ban;
    }
    float ha0 = 0.f, ha1 = 0.f, hb0 = 0.f, hb1 = 0.f;
#pragma unroll 2
    for (int s4 = 0; s4 < t0; s4 += 4) {
      const float4 wa = *(const float4*)&Wl[t0 + ta][s4];
      const float4 wb = *(const float4*)&Wl[t0 + tb2][s4];
      const float u0 = ul[s4 + 0][lane], u1 = ul[s4 + 1][lane];
      const float u2 = ul[s4 + 2][lane], u3 = ul[s4 + 3][lane];
      ha0 = __builtin_fmaf(wa.x, u0, ha0);
      ha1 = __builtin_fmaf(wa.y, u1, ha1);
      ha0 = __builtin_fmaf(wa.z, u2, ha0);
      ha1 = __builtin_fmaf(wa.w, u3, ha1);
      hb0 = __builtin_fmaf(wb.x, u0, hb0);
      hb1 = __builtin_fmaf(wb.y, u1, hb1);
      hb0 = __builtin_fmaf(wb.z, u2, hb0);
      hb1 = __builtin_fmaf(wb.w, u3, hb1);
    }
    zx[ta][lane] = za + (ha0 + ha1);
    zx[tb2][lane] = zb + (hb0 + hb1);
    __syncthreads();
    if (wave == 0) {
      float z[16], uv[16];
#pragma unroll
      for (int i = 0; i < 16; ++i) z[i] = zx[i][lane];
#pragma unroll
      for (int i = 0; i < 16; ++i) {
        const float u = sigmoid_f(z[i]);
        uv[i] = u;
        z0[((t0 + i) * B_ + b) * N_ + ncol] = u;  // in-place u
#pragma unroll
        for (int tt = i + 1; tt < 16; ++tt)
          z[tt] = __builtin_fmaf(u, Wl[t0 + tt][t0 + i], z[tt]);
      }
#pragma unroll
      for (int i = 0; i < 16; ++i) ul[t0 + i][lane] = uv[i];
    }
    __syncthreads();
    za = zna;
    zb = znb;
  }
}

// ---------------- np_final ----------------
__global__ void __launch_bounds__(512)
np_final(const float* __restrict__ ws, const float* __restrict__ w_final,
         const float* __restrict__ b_final, float* __restrict__ out) {
  const int wave = threadIdx.x >> 6, lane = threadIdx.x & 63;
  const int tb = blockIdx.x * 8 + wave;
  const float* u = ws + Z0_OFF + tb * N_ + lane * 8;
  const float4 a = *(const float4*)u, c = *(const float4*)(u + 4);
  const float4 wa = *(const float4*)&w_final[lane * 8];
  const float4 wc = *(const float4*)&w_final[lane * 8 + 4];
  float d = a.x * wa.x + a.y * wa.y + a.z * wa.z + a.w * wa.w +
            c.x * wc.x + c.y * wc.y + c.z * wc.z + c.w * wc.w;
  d = dpp_wave_sum(d);
  if (lane == 0) out[tb] = sigmoid_f(d + b_final[0]);
}

// ================= fallback path (R5) =================

__global__ void __launch_bounds__(512, 2)
fb_part1(const float* __restrict__ x, const float* __restrict__ w_mult,
         const float* __restrict__ b_mult, const float* __restrict__ p_lm,
         const float* __restrict__ p_em, float* __restrict__ ws) {
  const int g = blockIdx.x & 7, sub = blockIdx.x >> 3;
  const int wave = threadIdx.x >> 6, lane = threadIdx.x & 63;
  const int n0 = (sub * 8 + wave) * 2;
  __shared__ float xs[2][CH][D_];
  const float lam = sigmoid_f(p_lm[0]);
  const float eta = p_em[0];
  const v2f lam2 = v2(lam), klam2 = v2(1.f - lam);
  v2f wm[2][2], Bm[2][2];
  float bm[2];
#pragma unroll
  for (int r = 0; r < 2; ++r) {
    bm[r] = b_mult[n0 + r];
#pragma unroll
    for (int c = 0; c < 2; ++c) {
      wm[r][c] = *(const v2f*)&w_mult[(n0 + r) * D_ + c * 128 + 2 * lane];
      Bm[r][c] = v2(1.f);
    }
  }
  auto issue_stage = [&](int c) {
#pragma unroll
    for (int k = 0; k < 2; ++k) {
      const int row = k * 8 + wave;
      load_lds16(&x[((c * CH + row) * B_ + g) * D_ + 4 * lane],
                 &xs[c & 1][row][0]);
    }
  };
  issue_stage(0);
  __syncthreads();
  v2f xv[2][2];
  auto ldx = [&](int buf, int cb, int tl) {
    xv[buf][0] = *(const v2f*)&xs[cb][tl][2 * lane];
    xv[buf][1] = *(const v2f*)&xs[cb][tl][128 + 2 * lane];
  };
  for (int c = 0; c < NC; ++c) {
    if (c + 1 < NC) issue_stage(c + 1);
    const int cb = c & 1;
    ldx(0, cb, 0);
#pragma unroll
    for (int tl = 0; tl < CH; ++tl) {
      const int buf = tl & 1;
      if (tl + 1 < CH) ldx(buf ^ 1, cb, tl + 1);
      float hmv[2];
#pragma unroll
      for (int r = 0; r < 2; ++r) {
        v2f a = wm[r][0] * xv[buf][0] * Bm[r][0];
        a = __builtin_elementwise_fma(wm[r][1] * xv[buf][1], Bm[r][1], a);
        const float z = dpp_wave_sum(a.x + a.y) + bm[r];
        const float hm = tanh_f(z);
        hmv[r] = hm;
        const v2f c2 = v2(eta * hm);
#pragma unroll
        for (int cc = 0; cc < 2; ++cc) {
          v2f inner = __builtin_elementwise_fma(c2, xv[buf][cc], klam2);
          Bm[r][cc] = __builtin_elementwise_fma(lam2, Bm[r][cc], inner);
        }
      }
      if (lane == 0) {
        v2f hv2;
        hv2.x = hmv[0];
        hv2.y = hmv[1];
        *(v2f*)(ws + ((c * CH + tl) * B_ + g) * N_ + n0) = hv2;
      }
    }
    __syncthreads();
  }
}

__global__ void __launch_bounds__(512, 2)
fb_part2(const float* __restrict__ w_add, const float* __restrict__ b_add,
         const float* __restrict__ w_final, const float* __restrict__ p_la,
         const float* __restrict__ p_ea, float* __restrict__ ws) {
  const int g = blockIdx.x & 7, sub = blockIdx.x >> 3;
  const int wave = threadIdx.x >> 6, lane = threadIdx.x & 63;
  const int n0 = (sub * 8 + wave) * 2;
  __shared__ float hs[2][CH][N_];
  const float lam = sigmoid_f(p_la[0]);
  const float eta = p_ea[0];
  const v2f lam2 = v2(lam);
  const float klam = 1.f - lam;
  v2f Sa[2][4], wb[2][4];
  float ba[2], wf[2];
#pragma unroll
  for (int r = 0; r < 2; ++r) {
    ba[r] = b_add[n0 + r];
    wf[r] = w_final[n0 + r];
#pragma unroll
    for (int c = 0; c < 4; ++c) {
      const v2f wa = *(const v2f*)&w_add[(n0 + r) * N_ + c * 128 + 2 * lane];
      Sa[r][c] = wa;
      wb[r][c] = wa * klam;
    }
  }
  const float* hsrc = ws;
  float* part = ws + HOFF;
  auto issue_stage = [&](int c) {
#pragma unroll
    for (int k = 0; k < 2; ++k) {
      const int row = k * 8 + wave;
#pragma unroll
      for (int jj = 0; jj < 2; ++jj)
        load_lds16(&hsrc[((c * CH + row) * B_ + g) * N_ + jj * 256 + 4 * lane],
                   &hs[c & 1][row][jj * 256]);
    }
  };
  issue_stage(0);
  __syncthreads();
  v2f hv[2][4];
  auto ldh = [&](int buf, int cb, int tl) {
#pragma unroll
    for (int cc = 0; cc < 4; ++cc)
      hv[buf][cc] = *(const v2f*)&hs[cb][tl][cc * 128 + 2 * lane];
  };
  for (int c = 0; c < NC; ++c) {
    if (c + 1 < NC) issue_stage(c + 1);
    const int cb = c & 1;
    ldh(0, cb, 0);
#pragma unroll
    for (int tl = 0; tl < CH; ++tl) {
      const int buf = tl & 1;
      if (tl + 1 < CH) ldh(buf ^ 1, cb, tl + 1);
      float py = 0.f;
#pragma unroll
      for (int r = 0; r < 2; ++r) {
        v2f a0 = Sa[r][0] * hv[buf][0];
        v2f a1 = Sa[r][1] * hv[buf][1];
        a0 = __builtin_elementwise_fma(Sa[r][2], hv[buf][2], a0);
        a1 = __builtin_elementwise_fma(Sa[r][3], hv[buf][3], a1);
        const v2f a = a0 + a1;
        const float z = dpp_wave_sum(a.x + a.y) + ba[r];
        const float ha = sigmoid_f(z);
        const v2f c2 = v2(eta * ha);
#pragma unroll
        for (int cc = 0; cc < 4; ++cc) {
          v2f inner = __builtin_elementwise_fma(c2, hv[buf][cc], wb[r][cc]);
          Sa[r][cc] = __builtin_elementwise_fma(lam2, Sa[r][cc], inner);
        }
        py = __builtin_fmaf(wf[r], ha, py);
      }
      if (lane == 0)
        part[((c * CH + tl) * B_ + g) * 256 + sub * 8 + wave] = py;
    }
    __syncthreads();
  }
}

__global__ void __launch_bounds__(512)
fb_final(const float* __restrict__ ws, const float* __restrict__ b_final,
         float* __restrict__ out) {
  const int wave = threadIdx.x >> 6, lane = threadIdx.x & 63;
  const int tb = blockIdx.x * 8 + wave;
  const float4 v = *(const float4*)(ws + HOFF + tb * 256 + lane * 4);
  const float s = dpp_wave_sum((v.x + v.y) + (v.z + v.w));
  if (lane == 0) out[tb] = sigmoid_f(s + b_final[0]);
}

// ================= launch =================

extern "C" void kernel_launch(void* const* d_in, const int* in_sizes, int n_in,
                              void* d_out, int out_size, void* d_ws,
                              size_t ws_size, hipStream_t stream) {
  const float* x       = (const float*)d_in[0];
  const float* w_mult  = (const float*)d_in[1];
  const float* b_mult  = (const float*)d_in[2];
  const float* w_add   = (const float*)d_in[3];
  const float* b_add   = (const float*)d_in[4];
  const float* w_final = (const float*)d_in[5];
  const float* b_final = (const float*)d_in[6];
  const float* p_lm    = (const float*)d_in[7];
  const float* p_la    = (const float*)d_in[8];
  const float* p_em    = (const float*)d_in[9];
  const float* p_ea    = (const float*)d_in[10];
  float* out = (float*)d_out;
  float* ws  = (float*)d_ws;

  if (ws_size >= WS_NEED) {
    hipLaunchKernelGGL(np_part1, dim3(256), dim3(512), 0, stream,
                       x, w_mult, b_mult, p_lm, p_em, ws);
    hipLaunchKernelGGL(np_mid, dim3(2176), dim3(256), 0, stream,
                       w_add, p_la, p_ea, ws);
    hipLaunchKernelGGL(np_scan, dim3(64), dim3(512), 0, stream, b_add, ws);
    hipLaunchKernelGGL(np_final, dim3(128), dim3(512), 0, stream,
                       ws, w_final, b_final, out);
  } else {
    hipLaunchKernelGGL(fb_part1, dim3(256), dim3(512), 0, stream,
                       x, w_mult, b_mult, p_lm, p_em, ws);
    hipLaunchKernelGGL(fb_part2, dim3(256), dim3(512), 0, stream,
                       w_add, b_add, w_final, p_la, p_ea, ws);
    hipLaunchKernelGGL(fb_final, dim3(128), dim3(512), 0, stream,
                       ws, b_final, out);
  }
}

// Round 9
// 94.765 us; speedup vs baseline: 1.0803x; 1.0803x over previous
//
#include <hip/hip_runtime.h>
#include <cstdint>

// HebbFF T=128,B=8,N=512,D=256,O=1. Gram-matrix reformulation:
//   z(t) = w_add@h_m(t) + b_add + sum_{s<t} W[t][s] u(s),  u = sigmoid(z)
//   W[t][s] = eta_a * lam_a^(t-1-s) * (h_m(s).h_m(t))
// R9: np_mid base GEMM rebuilt for w-reuse:
//   - wT[k][n] pre-transpose of w_add, produced as a tail on the first 64
//     np_part1 blocks (no extra launch).
//   - base: 512 blocks = 128 pr-groups (4 hp rows in LDS, broadcast reads)
//     x 4 n-quarters, split-K=2; w reads coalesced from wT; 8-deep w
//     prefetch; LDS combine. w L2 traffic 256MB -> 64MB; 0 bank conflicts.
//   - gram unchanged.
// ws (floats): hp@0 (524288) | z0/u@524288 (524288) | W@1048576 (131072)
//   | wT@1179648 (262144) = 5.5 MB. Fallback to R5 path if ws too small.

#define T_ 128
#define B_ 8
#define N_ 512
#define D_ 256
#define HP_OFF 0
#define Z0_OFF 524288
#define WS_OFF 1048576
#define WT_OFF 1179648
#define WS_NEED ((size_t)(WT_OFF + 262144) * 4)
#define HOFF (T_ * B_ * N_)   // fallback layout
#define CH 16
#define NC (T_ / CH)

typedef float v2f __attribute__((ext_vector_type(2)));

__device__ __forceinline__ v2f v2(float s) { v2f r; r.x = s; r.y = s; return r; }
__device__ __forceinline__ v2f mk2(float a, float b) { v2f r; r.x = a; r.y = b; return r; }

__device__ __forceinline__ void load_lds16(const float* g, float* l) {
  __builtin_amdgcn_global_load_lds(
      (const __attribute__((address_space(1))) uint32_t*)(const void*)g,
      (__attribute__((address_space(3))) uint32_t*)(void*)l, 16, 0, 0);
}

#define DPP1(v, ctrl)                                                          \
  v += __int_as_float(                                                         \
      __builtin_amdgcn_update_dpp(0, __float_as_int(v), ctrl, 0xf, 0xf, true))

__device__ __forceinline__ float dpp_red(float v) {
  DPP1(v, 0x111); DPP1(v, 0x112); DPP1(v, 0x114); DPP1(v, 0x118);
  DPP1(v, 0x142); DPP1(v, 0x143);
  return v;
}
__device__ __forceinline__ v2f dpp_red2(v2f v) {
  float a = v.x, b = v.y;
  DPP1(a, 0x111); DPP1(b, 0x111); DPP1(a, 0x112); DPP1(b, 0x112);
  DPP1(a, 0x114); DPP1(b, 0x114); DPP1(a, 0x118); DPP1(b, 0x118);
  DPP1(a, 0x142); DPP1(b, 0x142); DPP1(a, 0x143); DPP1(b, 0x143);
  v.x = a; v.y = b;
  return v;
}
// 32-lane sum: lane31 = sum(0..31), lane63 = sum(32..63)
__device__ __forceinline__ float dpp_red1_32(float v) {
  DPP1(v, 0x111); DPP1(v, 0x112); DPP1(v, 0x114); DPP1(v, 0x118);
  DPP1(v, 0x142);
  return v;
}
__device__ __forceinline__ float dpp_wave_sum(float v) {
  v = dpp_red(v);
  return __int_as_float(__builtin_amdgcn_readlane(__float_as_int(v), 63));
}
__device__ __forceinline__ float sigmoid_f(float z) {
  return __builtin_amdgcn_rcpf(1.f + __expf(-z));
}
__device__ __forceinline__ float tanh_f(float z) {
  return 1.f - 2.f * __builtin_amdgcn_rcpf(1.f + __expf(2.f * z));
}

// ---------------- np_part1: h_mult / A_mult chain (32-lane split) ----------
// 256 blocks; blocks < 64 also transpose w_add -> wT as a tail.
__global__ void __launch_bounds__(512, 1)
np_part1(const float* __restrict__ x, const float* __restrict__ w_mult,
         const float* __restrict__ b_mult, const float* __restrict__ w_add,
         const float* __restrict__ p_lm, const float* __restrict__ p_em,
         float* __restrict__ ws) {
  const int g = blockIdx.x & 7, sub = blockIdx.x >> 3;
  const int wave = threadIdx.x >> 6, lane = threadIdx.x & 63;
  const int l31 = lane & 31, half = lane >> 5;
  const int n0 = (sub * 8 + wave) * 2;
  const int n = n0 + half;

  __shared__ float xs[T_][D_];  // 128 KB: ALL x rows for batch g
#pragma unroll
  for (int i = 0; i < 16; ++i) {
    const int r = wave * 16 + i;
    load_lds16(&x[(r * B_ + g) * D_ + 4 * lane], &xs[r][0]);
  }

  const float lam = sigmoid_f(p_lm[0]);
  const float eta = p_em[0];
  const v2f lam2 = v2(lam), klam2 = v2(1.f - lam);

  v2f wm[4], Bm[4];
#pragma unroll
  for (int c = 0; c < 4; ++c) {
    wm[c] = *(const v2f*)&w_mult[n * D_ + 64 * c + 2 * l31];
    Bm[c] = v2(1.f);
  }
  const float bm = b_mult[n];
  __syncthreads();  // x staged (drains vmcnt)

  float* hp = ws + HP_OFF;
  v2f xv[4][4];  // 4-slot ring, 3-ahead prefetch
#define LDX(slot, t)                                                           \
  {                                                                            \
    _Pragma("unroll") for (int c = 0; c < 4; ++c)                              \
        xv[slot][c] = *(const v2f*)&xs[t][64 * c + 2 * l31];                   \
  }
  LDX(0, 0) LDX(1, 1) LDX(2, 2)

  float ph = 0.f;
  for (int t4 = 0; t4 < T_; t4 += 4) {
#pragma unroll
    for (int j = 0; j < 4; ++j) {
      const int t = t4 + j;
      if (t + 3 < T_) LDX((j + 3) & 3, t + 3)
      v2f wx = wm[0] * xv[j][0];
      v2f a = wx * Bm[0];
#pragma unroll
      for (int c = 1; c < 4; ++c) {
        wx = wm[c] * xv[j][c];
        a = __builtin_elementwise_fma(wx, Bm[c], a);
      }
      float s = dpp_red1_32(a.x + a.y);
      const float zr0 =
          __int_as_float(__builtin_amdgcn_readlane(__float_as_int(s), 31));
      const float zr1 =
          __int_as_float(__builtin_amdgcn_readlane(__float_as_int(s), 63));
      const float zz = (half ? zr1 : zr0) + bm;
      const float hm = tanh_f(zz);
      const v2f c2 = v2(eta * hm);
#pragma unroll
      for (int c = 0; c < 4; ++c) {
        v2f inner = __builtin_elementwise_fma(c2, xv[j][c], klam2);
        Bm[c] = __builtin_elementwise_fma(lam2, Bm[c], inner);
      }
      if (j & 1) {
        if (l31 == 31)
          *(v2f*)(hp + (size_t)((t >> 1) * B_ + g) * (N_ * 2) + n * 2) =
              mk2(ph, hm);
      } else {
        ph = hm;
      }
    }
  }
#undef LDX

  // ---- tail: blocks 0..63 transpose w_add (512x512) -> wT[k][n] ----
  if (blockIdx.x < 64) {
    float* wT = ws + WT_OFF;
    const int nrow = blockIdx.x * 8 + (threadIdx.x >> 6);
    const int seg = threadIdx.x & 63;
    const float4 a0 = *(const float4*)&w_add[nrow * N_ + seg * 8];
    const float4 a1 = *(const float4*)&w_add[nrow * N_ + seg * 8 + 4];
    float v[8] = {a0.x, a0.y, a0.z, a0.w, a1.x, a1.y, a1.z, a1.w};
#pragma unroll
    for (int i = 0; i < 8; ++i) wT[(seg * 8 + i) * N_ + nrow] = v[i];
  }
}

// ---------------- np_mid: base GEMM (wT, split-K) + Gram ----------------
// 640 blocks x 256 thr: [0,512) base; [512,640) gram.
__global__ void __launch_bounds__(256, 2)
np_mid(const float* __restrict__ w_add, const float* __restrict__ p_la,
       const float* __restrict__ p_ea, float* __restrict__ ws) {
  __shared__ float hl[4096];    // 16 KB
  __shared__ float zs[4][256];  // 4 KB combine buffer
  const int wave = threadIdx.x >> 6, lane = threadIdx.x & 63;
  const float* hp = ws + HP_OFF;
  float* z0 = ws + Z0_OFF;
  float* Wsc = ws + WS_OFF;

  if (blockIdx.x < 512) {
    // ---- base: pr-group (4 hp rows) x n-quarter (128), split-K=2 ----
    const int pg = blockIdx.x >> 2;   // 0..127
    const int nq = blockIdx.x & 3;
    // stage 4 hp rows (16 KB): wave w -> row pg*4+w
#pragma unroll
    for (int i = 0; i < 4; ++i)
      load_lds16(&hp[(pg * 4 + wave) * 1024 + i * 256 + 4 * lane],
                 &hl[wave * 1024 + i * 256]);
    __syncthreads();

    const int tid = threadIdx.x;
    const int kh = tid >> 7, nl = tid & 127;
    const int n = nq * 128 + nl;
    const int k0 = kh * 256;
    const float* wb = ws + WT_OFF + n;  // + k*512

    float wc[8], wn[8];
#pragma unroll
    for (int j = 0; j < 8; ++j) wc[j] = wb[(k0 + j) * N_];

    v2f acc[4] = {v2(0.f), v2(0.f), v2(0.f), v2(0.f)};
    for (int k8 = 0; k8 < 32; ++k8) {
      const int k = k0 + k8 * 8;
      if (k8 + 1 < 32) {
#pragma unroll
        for (int j = 0; j < 8; ++j) wn[j] = wb[(k + 8 + j) * N_];
      }
#pragma unroll
      for (int p = 0; p < 4; ++p) {
        const float4* h4 = (const float4*)&hl[p * 1024 + 2 * k];
        const float4 ha = h4[0], hb = h4[1], hc = h4[2], hd = h4[3];
        acc[p] = __builtin_elementwise_fma(mk2(ha.x, ha.y), v2(wc[0]), acc[p]);
        acc[p] = __builtin_elementwise_fma(mk2(ha.z, ha.w), v2(wc[1]), acc[p]);
        acc[p] = __builtin_elementwise_fma(mk2(hb.x, hb.y), v2(wc[2]), acc[p]);
        acc[p] = __builtin_elementwise_fma(mk2(hb.z, hb.w), v2(wc[3]), acc[p]);
        acc[p] = __builtin_elementwise_fma(mk2(hc.x, hc.y), v2(wc[4]), acc[p]);
        acc[p] = __builtin_elementwise_fma(mk2(hc.z, hc.w), v2(wc[5]), acc[p]);
        acc[p] = __builtin_elementwise_fma(mk2(hd.x, hd.y), v2(wc[6]), acc[p]);
        acc[p] = __builtin_elementwise_fma(mk2(hd.z, hd.w), v2(wc[7]), acc[p]);
      }
#pragma unroll
      for (int j = 0; j < 8; ++j) wc[j] = wn[j];
    }
    // combine k-halves via LDS
    if (kh) {
#pragma unroll
      for (int p = 0; p < 4; ++p) *(v2f*)&zs[p][2 * nl] = acc[p];
    }
    __syncthreads();
    if (!kh) {
#pragma unroll
      for (int p = 0; p < 4; ++p) {
        const v2f t = acc[p] + *(const v2f*)&zs[p][2 * nl];
        const int pr = pg * 4 + p;
        const int rowe = 16 * (pr >> 3) + (pr & 7);
        z0[rowe * N_ + n] = t.x;
        z0[(rowe + 8) * N_ + n] = t.y;
      }
    }
  } else {
    // ---- gram: block (b, q): t rows [8q, 8q+8) vs s < t ----
    const int bi2 = blockIdx.x - 512;
    const int b = bi2 & 7, q = bi2 >> 3;
    const float lam = sigmoid_f(p_la[0]);
    const float eta = p_ea[0];
#pragma unroll
    for (int i = 0; i < 4; ++i)
      load_lds16(&hp[((q * 4 + wave) * 8 + b) * 1024 + i * 256 + 4 * lane],
                 &hl[wave * 1024 + i * 256]);
    __syncthreads();
    v2f hv[4][8];
#pragma unroll
    for (int i = 0; i < 4; ++i)
#pragma unroll
      for (int j = 0; j < 8; ++j)
        hv[i][j] = ((const v2f*)hl)[i * 512 + lane + 64 * j];

    const float l2lam = __log2f(lam);
    const int tlim = q * 8 + 7;
    float wv[8], wvn[8];
    auto loadg = [&](float* dst, int tp) {
      const float* hrow = hp + ((tp >> 1) * 8 + b) * 1024 + (tp & 1);
#pragma unroll
      for (int j = 0; j < 8; ++j) dst[j] = hrow[2 * (lane + 64 * j)];
    };
    if (wave < tlim) loadg(wv, wave);
    for (int tp = wave; tp < tlim; tp += 4) {
      if (tp + 4 < tlim) loadg(wvn, tp + 4);
#pragma unroll
      for (int i = 0; i < 4; ++i) {
        v2f a = hv[i][0] * v2(wv[0]);
#pragma unroll
        for (int j = 1; j < 8; ++j)
          a = __builtin_elementwise_fma(hv[i][j], v2(wv[j]), a);
        a = dpp_red2(a);
        if (lane == 63) {
          const int te = q * 8 + 2 * i;
          if (tp < te)
            Wsc[(b * T_ + te) * T_ + tp] =
                eta * exp2f(l2lam * (float)(te - 1 - tp)) * a.x;
          if (tp < te + 1)
            Wsc[(b * T_ + te + 1) * T_ + tp] =
                eta * exp2f(l2lam * (float)(te - tp)) * a.y;
        }
      }
#pragma unroll
      for (int j = 0; j < 8; ++j) wv[j] = wvn[j];
    }
  }
}

// ---------------- np_scan: sequential sigmoid scan ----------------
__global__ void __launch_bounds__(512, 1)
np_scan(const float* __restrict__ b_add, float* __restrict__ ws) {
  __shared__ float Wl[T_][T_];   // 64 KB
  __shared__ float ul[T_][64];   // 32 KB
  __shared__ float zx[16][64];   // 4 KB
  const int b = blockIdx.x >> 3, nc = blockIdx.x & 7;
  const int wave = threadIdx.x >> 6, lane = threadIdx.x & 63;
  float* z0 = ws + Z0_OFF;
  const float* Wb = ws + WS_OFF + b * T_ * T_;

#pragma unroll
  for (int i = 0; i < 8; ++i) {
    const int r2 = wave * 16 + i * 2;
    load_lds16(&Wb[r2 * T_ + 4 * lane], &Wl[r2][0]);
  }

  const int ta = 2 * wave, tb2 = 2 * wave + 1;
  const int ncol = nc * 64 + lane;
  const float ban = b_add[ncol];

  float za = z0[(ta * B_ + b) * N_ + ncol] + ban;
  float zb = z0[(tb2 * B_ + b) * N_ + ncol] + ban;
  __syncthreads();  // W staged

  for (int j = 0; j < 8; ++j) {
    const int t0 = j * 16;
    float zna = 0.f, znb = 0.f;
    if (j < 7) {
      zna = z0[((t0 + 16 + ta) * B_ + b) * N_ + ncol] + ban;
      znb = z0[((t0 + 16 + tb2) * B_ + b) * N_ + ncol] + ban;
    }
    float ha0 = 0.f, ha1 = 0.f, hb0 = 0.f, hb1 = 0.f;
#pragma unroll 2
    for (int s4 = 0; s4 < t0; s4 += 4) {
      const float4 wa = *(const float4*)&Wl[t0 + ta][s4];
      const float4 wb = *(const float4*)&Wl[t0 + tb2][s4];
      const float u0 = ul[s4 + 0][lane], u1 = ul[s4 + 1][lane];
      const float u2 = ul[s4 + 2][lane], u3 = ul[s4 + 3][lane];
      ha0 = __builtin_fmaf(wa.x, u0, ha0);
      ha1 = __builtin_fmaf(wa.y, u1, ha1);
      ha0 = __builtin_fmaf(wa.z, u2, ha0);
      ha1 = __builtin_fmaf(wa.w, u3, ha1);
      hb0 = __builtin_fmaf(wb.x, u0, hb0);
      hb1 = __builtin_fmaf(wb.y, u1, hb1);
      hb0 = __builtin_fmaf(wb.z, u2, hb0);
      hb1 = __builtin_fmaf(wb.w, u3, hb1);
    }
    zx[ta][lane] = za + (ha0 + ha1);
    zx[tb2][lane] = zb + (hb0 + hb1);
    __syncthreads();
    if (wave == 0) {
      float z[16], uv[16];
#pragma unroll
      for (int i = 0; i < 16; ++i) z[i] = zx[i][lane];
#pragma unroll
      for (int i = 0; i < 16; ++i) {
        const float u = sigmoid_f(z[i]);
        uv[i] = u;
        z0[((t0 + i) * B_ + b) * N_ + ncol] = u;  // in-place u
#pragma unroll
        for (int tt = i + 1; tt < 16; ++tt)
          z[tt] = __builtin_fmaf(u, Wl[t0 + tt][t0 + i], z[tt]);
      }
#pragma unroll
      for (int i = 0; i < 16; ++i) ul[t0 + i][lane] = uv[i];
    }
    __syncthreads();
    za = zna;
    zb = znb;
  }
}

// ---------------- np_final ----------------
__global__ void __launch_bounds__(512)
np_final(const float* __restrict__ ws, const float* __restrict__ w_final,
         const float* __restrict__ b_final, float* __restrict__ out) {
  const int wave = threadIdx.x >> 6, lane = threadIdx.x & 63;
  const int tb = blockIdx.x * 8 + wave;
  const float* u = ws + Z0_OFF + tb * N_ + lane * 8;
  const float4 a = *(const float4*)u, c = *(const float4*)(u + 4);
  const float4 wa = *(const float4*)&w_final[lane * 8];
  const float4 wc = *(const float4*)&w_final[lane * 8 + 4];
  float d = a.x * wa.x + a.y * wa.y + a.z * wa.z + a.w * wa.w +
            c.x * wc.x + c.y * wc.y + c.z * wc.z + c.w * wc.w;
  d = dpp_wave_sum(d);
  if (lane == 0) out[tb] = sigmoid_f(d + b_final[0]);
}

// ================= fallback path (R5) =================

__global__ void __launch_bounds__(512, 2)
fb_part1(const float* __restrict__ x, const float* __restrict__ w_mult,
         const float* __restrict__ b_mult, const float* __restrict__ p_lm,
         const float* __restrict__ p_em, float* __restrict__ ws) {
  const int g = blockIdx.x & 7, sub = blockIdx.x >> 3;
  const int wave = threadIdx.x >> 6, lane = threadIdx.x & 63;
  const int n0 = (sub * 8 + wave) * 2;
  __shared__ float xs[2][CH][D_];
  const float lam = sigmoid_f(p_lm[0]);
  const float eta = p_em[0];
  const v2f lam2 = v2(lam), klam2 = v2(1.f - lam);
  v2f wm[2][2], Bm[2][2];
  float bm[2];
#pragma unroll
  for (int r = 0; r < 2; ++r) {
    bm[r] = b_mult[n0 + r];
#pragma unroll
    for (int c = 0; c < 2; ++c) {
      wm[r][c] = *(const v2f*)&w_mult[(n0 + r) * D_ + c * 128 + 2 * lane];
      Bm[r][c] = v2(1.f);
    }
  }
  auto issue_stage = [&](int c) {
#pragma unroll
    for (int k = 0; k < 2; ++k) {
      const int row = k * 8 + wave;
      load_lds16(&x[((c * CH + row) * B_ + g) * D_ + 4 * lane],
                 &xs[c & 1][row][0]);
    }
  };
  issue_stage(0);
  __syncthreads();
  v2f xv[2][2];
  auto ldx = [&](int buf, int cb, int tl) {
    xv[buf][0] = *(const v2f*)&xs[cb][tl][2 * lane];
    xv[buf][1] = *(const v2f*)&xs[cb][tl][128 + 2 * lane];
  };
  for (int c = 0; c < NC; ++c) {
    if (c + 1 < NC) issue_stage(c + 1);
    const int cb = c & 1;
    ldx(0, cb, 0);
#pragma unroll
    for (int tl = 0; tl < CH; ++tl) {
      const int buf = tl & 1;
      if (tl + 1 < CH) ldx(buf ^ 1, cb, tl + 1);
      float hmv[2];
#pragma unroll
      for (int r = 0; r < 2; ++r) {
        v2f a = wm[r][0] * xv[buf][0] * Bm[r][0];
        a = __builtin_elementwise_fma(wm[r][1] * xv[buf][1], Bm[r][1], a);
        const float z = dpp_wave_sum(a.x + a.y) + bm[r];
        const float hm = tanh_f(z);
        hmv[r] = hm;
        const v2f c2 = v2(eta * hm);
#pragma unroll
        for (int cc = 0; cc < 2; ++cc) {
          v2f inner = __builtin_elementwise_fma(c2, xv[buf][cc], klam2);
          Bm[r][cc] = __builtin_elementwise_fma(lam2, Bm[r][cc], inner);
        }
      }
      if (lane == 0) {
        v2f hv2;
        hv2.x = hmv[0];
        hv2.y = hmv[1];
        *(v2f*)(ws + ((c * CH + tl) * B_ + g) * N_ + n0) = hv2;
      }
    }
    __syncthreads();
  }
}

__global__ void __launch_bounds__(512, 2)
fb_part2(const float* __restrict__ w_add, const float* __restrict__ b_add,
         const float* __restrict__ w_final, const float* __restrict__ p_la,
         const float* __restrict__ p_ea, float* __restrict__ ws) {
  const int g = blockIdx.x & 7, sub = blockIdx.x >> 3;
  const int wave = threadIdx.x >> 6, lane = threadIdx.x & 63;
  const int n0 = (sub * 8 + wave) * 2;
  __shared__ float hs[2][CH][N_];
  const float lam = sigmoid_f(p_la[0]);
  const float eta = p_ea[0];
  const v2f lam2 = v2(lam);
  const float klam = 1.f - lam;
  v2f Sa[2][4], wb[2][4];
  float ba[2], wf[2];
#pragma unroll
  for (int r = 0; r < 2; ++r) {
    ba[r] = b_add[n0 + r];
    wf[r] = w_final[n0 + r];
#pragma unroll
    for (int c = 0; c < 4; ++c) {
      const v2f wa = *(const v2f*)&w_add[(n0 + r) * N_ + c * 128 + 2 * lane];
      Sa[r][c] = wa;
      wb[r][c] = wa * klam;
    }
  }
  const float* hsrc = ws;
  float* part = ws + HOFF;
  auto issue_stage = [&](int c) {
#pragma unroll
    for (int k = 0; k < 2; ++k) {
      const int row = k * 8 + wave;
#pragma unroll
      for (int jj = 0; jj < 2; ++jj)
        load_lds16(&hsrc[((c * CH + row) * B_ + g) * N_ + jj * 256 + 4 * lane],
                   &hs[c & 1][row][jj * 256]);
    }
  };
  issue_stage(0);
  __syncthreads();
  v2f hv[2][4];
  auto ldh = [&](int buf, int cb, int tl) {
#pragma unroll
    for (int cc = 0; cc < 4; ++cc)
      hv[buf][cc] = *(const v2f*)&hs[cb][tl][cc * 128 + 2 * lane];
  };
  for (int c = 0; c < NC; ++c) {
    if (c + 1 < NC) issue_stage(c + 1);
    const int cb = c & 1;
    ldh(0, cb, 0);
#pragma unroll
    for (int tl = 0; tl < CH; ++tl) {
      const int buf = tl & 1;
      if (tl + 1 < CH) ldh(buf ^ 1, cb, tl + 1);
      float py = 0.f;
#pragma unroll
      for (int r = 0; r < 2; ++r) {
        v2f a0 = Sa[r][0] * hv[buf][0];
        v2f a1 = Sa[r][1] * hv[buf][1];
        a0 = __builtin_elementwise_fma(Sa[r][2], hv[buf][2], a0);
        a1 = __builtin_elementwise_fma(Sa[r][3], hv[buf][3], a1);
        const v2f a = a0 + a1;
        const float z = dpp_wave_sum(a.x + a.y) + ba[r];
        const float ha = sigmoid_f(z);
        const v2f c2 = v2(eta * ha);
#pragma unroll
        for (int cc = 0; cc < 4; ++cc) {
          v2f inner = __builtin_elementwise_fma(c2, hv[buf][cc], wb[r][cc]);
          Sa[r][cc] = __builtin_elementwise_fma(lam2, Sa[r][cc], inner);
        }
        py = __builtin_fmaf(wf[r], ha, py);
      }
      if (lane == 0)
        part[((c * CH + tl) * B_ + g) * 256 + sub * 8 + wave] = py;
    }
    __syncthreads();
  }
}

__global__ void __launch_bounds__(512)
fb_final(const float* __restrict__ ws, const float* __restrict__ b_final,
         float* __restrict__ out) {
  const int wave = threadIdx.x >> 6, lane = threadIdx.x & 63;
  const int tb = blockIdx.x * 8 + wave;
  const float4 v = *(const float4*)(ws + HOFF + tb * 256 + lane * 4);
  const float s = dpp_wave_sum((v.x + v.y) + (v.z + v.w));
  if (lane == 0) out[tb] = sigmoid_f(s + b_final[0]);
}

// ================= launch =================

extern "C" void kernel_launch(void* const* d_in, const int* in_sizes, int n_in,
                              void* d_out, int out_size, void* d_ws,
                              size_t ws_size, hipStream_t stream) {
  const float* x       = (const float*)d_in[0];
  const float* w_mult  = (const float*)d_in[1];
  const float* b_mult  = (const float*)d_in[2];
  const float* w_add   = (const float*)d_in[3];
  const float* b_add   = (const float*)d_in[4];
  const float* w_final = (const float*)d_in[5];
  const float* b_final = (const float*)d_in[6];
  const float* p_lm    = (const float*)d_in[7];
  const float* p_la    = (const float*)d_in[8];
  const float* p_em    = (const float*)d_in[9];
  const float* p_ea    = (const float*)d_in[10];
  float* out = (float*)d_out;
  float* ws  = (float*)d_ws;

  if (ws_size >= WS_NEED) {
    hipLaunchKernelGGL(np_part1, dim3(256), dim3(512), 0, stream,
                       x, w_mult, b_mult, w_add, p_lm, p_em, ws);
    hipLaunchKernelGGL(np_mid, dim3(640), dim3(256), 0, stream,
                       w_add, p_la, p_ea, ws);
    hipLaunchKernelGGL(np_scan, dim3(64), dim3(512), 0, stream, b_add, ws);
    hipLaunchKernelGGL(np_final, dim3(128), dim3(512), 0, stream,
                       ws, w_final, b_final, out);
  } else {
    hipLaunchKernelGGL(fb_part1, dim3(256), dim3(512), 0, stream,
                       x, w_mult, b_mult, p_lm, p_em, ws);
    hipLaunchKernelGGL(fb_part2, dim3(256), dim3(512), 0, stream,
                       w_add, b_add, w_final, p_la, p_ea, ws);
    hipLaunchKernelGGL(fb_final, dim3(128), dim3(512), 0, stream,
                       ws, b_final, out);
  }
}

// Round 10
// 88.459 us; speedup vs baseline: 1.1573x; 1.0713x over previous
//
#include <hip/hip_runtime.h>
#include <cstdint>

// HebbFF T=128,B=8,N=512,D=256,O=1. Gram-matrix reformulation:
//   z(t) = w_add@h_m(t) + b_add + sum_{s<t} W[t][s] u(s),  u = sigmoid(z)
//   W[t][s] = eta_a * lam_a^(t-1-s) * (h_m(s).h_m(t))
// R10:
//   np_part1: h_mult chain (32-lane split), x fully LDS-staged. No transpose.
//   np_mid:   ONE kernel, 1088 blocks x 512 thr.
//             blocks [0,64): gram, balanced q-pairs {qq, 15-qq} (8 waves =
//               two 4-wave halves running R9's gram for q_lo/q_hi).
//             blocks [64,1088): base GEMM, R8 inner loop: h-frags in regs
//               (one-time LDS read), w_add read direct coalesced float4,
//               dpp_red2_32 reduce. Zero LDS in inner loop.
//   np_scan:  W_b in LDS; 16-tiles: parallel history FMA + wave0 triangle;
//             b_add folded at load.
//   np_final: y = sigmoid(w_final.u + b_final).
// ws (floats): hp@0 (524288) | z0/u@524288 (524288) | W@1048576 (131072).
// Fallback to R5 path if ws too small.

#define T_ 128
#define B_ 8
#define N_ 512
#define D_ 256
#define HP_OFF 0
#define Z0_OFF 524288
#define WS_OFF 1048576
#define WS_NEED ((size_t)(1048576 + 131072) * 4)
#define HOFF (T_ * B_ * N_)   // fallback layout
#define CH 16
#define NC (T_ / CH)

typedef float v2f __attribute__((ext_vector_type(2)));

__device__ __forceinline__ v2f v2(float s) { v2f r; r.x = s; r.y = s; return r; }
__device__ __forceinline__ v2f mk2(float a, float b) { v2f r; r.x = a; r.y = b; return r; }

__device__ __forceinline__ void load_lds16(const float* g, float* l) {
  __builtin_amdgcn_global_load_lds(
      (const __attribute__((address_space(1))) uint32_t*)(const void*)g,
      (__attribute__((address_space(3))) uint32_t*)(void*)l, 16, 0, 0);
}

#define DPP1(v, ctrl)                                                          \
  v += __int_as_float(                                                         \
      __builtin_amdgcn_update_dpp(0, __float_as_int(v), ctrl, 0xf, 0xf, true))

__device__ __forceinline__ float dpp_red(float v) {
  DPP1(v, 0x111); DPP1(v, 0x112); DPP1(v, 0x114); DPP1(v, 0x118);
  DPP1(v, 0x142); DPP1(v, 0x143);
  return v;
}
__device__ __forceinline__ v2f dpp_red2(v2f v) {
  float a = v.x, b = v.y;
  DPP1(a, 0x111); DPP1(b, 0x111); DPP1(a, 0x112); DPP1(b, 0x112);
  DPP1(a, 0x114); DPP1(b, 0x114); DPP1(a, 0x118); DPP1(b, 0x118);
  DPP1(a, 0x142); DPP1(b, 0x142); DPP1(a, 0x143); DPP1(b, 0x143);
  v.x = a; v.y = b;
  return v;
}
// 32-lane sum: lane31 = sum(0..31), lane63 = sum(32..63)
__device__ __forceinline__ float dpp_red1_32(float v) {
  DPP1(v, 0x111); DPP1(v, 0x112); DPP1(v, 0x114); DPP1(v, 0x118);
  DPP1(v, 0x142);
  return v;
}
__device__ __forceinline__ v2f dpp_red2_32(v2f v) {
  float a = v.x, b = v.y;
  DPP1(a, 0x111); DPP1(b, 0x111); DPP1(a, 0x112); DPP1(b, 0x112);
  DPP1(a, 0x114); DPP1(b, 0x114); DPP1(a, 0x118); DPP1(b, 0x118);
  DPP1(a, 0x142); DPP1(b, 0x142);
  v.x = a; v.y = b;
  return v;
}
__device__ __forceinline__ float dpp_wave_sum(float v) {
  v = dpp_red(v);
  return __int_as_float(__builtin_amdgcn_readlane(__float_as_int(v), 63));
}
__device__ __forceinline__ float sigmoid_f(float z) {
  return __builtin_amdgcn_rcpf(1.f + __expf(-z));
}
__device__ __forceinline__ float tanh_f(float z) {
  return 1.f - 2.f * __builtin_amdgcn_rcpf(1.f + __expf(2.f * z));
}

// ---------------- np_part1: h_mult / A_mult chain (32-lane split) ----------
__global__ void __launch_bounds__(512, 1)
np_part1(const float* __restrict__ x, const float* __restrict__ w_mult,
         const float* __restrict__ b_mult, const float* __restrict__ p_lm,
         const float* __restrict__ p_em, float* __restrict__ ws) {
  const int g = blockIdx.x & 7, sub = blockIdx.x >> 3;
  const int wave = threadIdx.x >> 6, lane = threadIdx.x & 63;
  const int l31 = lane & 31, half = lane >> 5;
  const int n0 = (sub * 8 + wave) * 2;
  const int n = n0 + half;

  __shared__ float xs[T_][D_];  // 128 KB: ALL x rows for batch g
#pragma unroll
  for (int i = 0; i < 16; ++i) {
    const int r = wave * 16 + i;
    load_lds16(&x[(r * B_ + g) * D_ + 4 * lane], &xs[r][0]);
  }

  const float lam = sigmoid_f(p_lm[0]);
  const float eta = p_em[0];
  const v2f lam2 = v2(lam), klam2 = v2(1.f - lam);

  v2f wm[4], Bm[4];
#pragma unroll
  for (int c = 0; c < 4; ++c) {
    wm[c] = *(const v2f*)&w_mult[n * D_ + 64 * c + 2 * l31];
    Bm[c] = v2(1.f);
  }
  const float bm = b_mult[n];
  __syncthreads();  // x staged (drains vmcnt)

  float* hp = ws + HP_OFF;
  v2f xv[4][4];  // 4-slot ring, 3-ahead prefetch
#define LDX(slot, t)                                                           \
  {                                                                            \
    _Pragma("unroll") for (int c = 0; c < 4; ++c)                              \
        xv[slot][c] = *(const v2f*)&xs[t][64 * c + 2 * l31];                   \
  }
  LDX(0, 0) LDX(1, 1) LDX(2, 2)

  float ph = 0.f;
  for (int t4 = 0; t4 < T_; t4 += 4) {
#pragma unroll
    for (int j = 0; j < 4; ++j) {
      const int t = t4 + j;
      if (t + 3 < T_) LDX((j + 3) & 3, t + 3)
      v2f wx = wm[0] * xv[j][0];
      v2f a = wx * Bm[0];
#pragma unroll
      for (int c = 1; c < 4; ++c) {
        wx = wm[c] * xv[j][c];
        a = __builtin_elementwise_fma(wx, Bm[c], a);
      }
      float s = dpp_red1_32(a.x + a.y);
      const float zr0 =
          __int_as_float(__builtin_amdgcn_readlane(__float_as_int(s), 31));
      const float zr1 =
          __int_as_float(__builtin_amdgcn_readlane(__float_as_int(s), 63));
      const float zz = (half ? zr1 : zr0) + bm;
      const float hm = tanh_f(zz);
      const v2f c2 = v2(eta * hm);
#pragma unroll
      for (int c = 0; c < 4; ++c) {
        v2f inner = __builtin_elementwise_fma(c2, xv[j][c], klam2);
        Bm[c] = __builtin_elementwise_fma(lam2, Bm[c], inner);
      }
      if (j & 1) {
        if (l31 == 31)
          *(v2f*)(hp + (size_t)((t >> 1) * B_ + g) * (N_ * 2) + n * 2) =
              mk2(ph, hm);
      } else {
        ph = hm;
      }
    }
  }
#undef LDX
}

// ---------------- np_mid: gram (balanced) + base GEMM ----------------
// 1088 blocks x 512 thr. [0,64): gram; [64,1088): base.
__global__ void __launch_bounds__(512)
np_mid(const float* __restrict__ w_add, const float* __restrict__ p_la,
       const float* __restrict__ p_ea, float* __restrict__ ws) {
  __shared__ float hl[8192];  // 32 KB (gram: 2x16KB halves; base: 4KB)
  const int wave = threadIdx.x >> 6, lane = threadIdx.x & 63;
  const float* hp = ws + HP_OFF;
  float* z0 = ws + Z0_OFF;
  float* Wsc = ws + WS_OFF;

  if (blockIdx.x < 64) {
    // ---- gram: block (b, qq): halves handle q = qq and q = 15-qq ----
    const int b = blockIdx.x & 7, qq = blockIdx.x >> 3;
    const int hlf = wave >> 2, w4 = wave & 3;
    const int q = hlf ? (15 - qq) : qq;
    float* hb = hl + hlf * 4096;
    const float lam = sigmoid_f(p_la[0]);
    const float eta = p_ea[0];
#pragma unroll
    for (int i = 0; i < 4; ++i)
      load_lds16(&hp[((q * 4 + w4) * 8 + b) * 1024 + i * 256 + 4 * lane],
                 &hb[w4 * 1024 + i * 256]);
    __syncthreads();
    v2f hv[4][8];
#pragma unroll
    for (int i = 0; i < 4; ++i)
#pragma unroll
      for (int j = 0; j < 8; ++j)
        hv[i][j] = ((const v2f*)hb)[i * 512 + lane + 64 * j];

    const float l2lam = __log2f(lam);
    const int tlim = q * 8 + 7;
    float wv[8], wvn[8];
    auto loadg = [&](float* dst, int tp) {
      const float* hrow = hp + ((tp >> 1) * 8 + b) * 1024 + (tp & 1);
#pragma unroll
      for (int j = 0; j < 8; ++j) dst[j] = hrow[2 * (lane + 64 * j)];
    };
    if (w4 < tlim) loadg(wv, w4);
    for (int tp = w4; tp < tlim; tp += 4) {
      if (tp + 4 < tlim) loadg(wvn, tp + 4);
#pragma unroll
      for (int i = 0; i < 4; ++i) {
        v2f a = hv[i][0] * v2(wv[0]);
#pragma unroll
        for (int j = 1; j < 8; ++j)
          a = __builtin_elementwise_fma(hv[i][j], v2(wv[j]), a);
        a = dpp_red2(a);
        if (lane == 63) {
          const int te = q * 8 + 2 * i;
          if (tp < te)
            Wsc[(b * T_ + te) * T_ + tp] =
                eta * exp2f(l2lam * (float)(te - 1 - tp)) * a.x;
          if (tp < te + 1)
            Wsc[(b * T_ + te + 1) * T_ + tp] =
                eta * exp2f(l2lam * (float)(te - tp)) * a.y;
        }
      }
#pragma unroll
      for (int j = 0; j < 8; ++j) wv[j] = wvn[j];
    }
  } else {
    // ---- base: pr-row x 256 n; h-frags in regs, w_add direct ----
    const int bx = blockIdx.x - 64;
    const int pr = bx >> 1;          // hp row = t2*8 + b, 0..511
    const int nh = bx & 1;
    if (wave < 4)
      load_lds16(&hp[pr * 1024 + wave * 256 + 4 * lane], &hl[wave * 256]);
    __syncthreads();

    const int l31 = lane & 31, half = lane >> 5;
    // h fragments: k = 4*l31 + kk + 128*jj (kk in [0,4)); pairs at hl[2k..]
    float4 hfa[4], hfb[4];
#pragma unroll
    for (int jj = 0; jj < 4; ++jj) {
      hfa[jj] = *(const float4*)&hl[256 * jj + 8 * l31];      // kk=0,1
      hfb[jj] = *(const float4*)&hl[256 * jj + 8 * l31 + 4];  // kk=2,3
    }
    const int rowe = 16 * (pr >> 3) + (pr & 7);  // t-even z0 row
    const int nbase = nh * 256 + wave * 32;
    float4 wc[4], wn[4];
    auto loadw = [&](float4* dst, int n_) {
      const float* wr = w_add + (size_t)n_ * N_ + 4 * l31;
#pragma unroll
      for (int jj = 0; jj < 4; ++jj) dst[jj] = *(const float4*)&wr[128 * jj];
    };
    loadw(wc, nbase + half);
    for (int i = 0; i < 16; ++i) {
      if (i + 1 < 16) loadw(wn, nbase + 2 * (i + 1) + half);
      v2f a = v2(0.f);
#pragma unroll
      for (int jj = 0; jj < 4; ++jj) {
        a = __builtin_elementwise_fma(mk2(hfa[jj].x, hfa[jj].y), v2(wc[jj].x), a);
        a = __builtin_elementwise_fma(mk2(hfa[jj].z, hfa[jj].w), v2(wc[jj].y), a);
        a = __builtin_elementwise_fma(mk2(hfb[jj].x, hfb[jj].y), v2(wc[jj].z), a);
        a = __builtin_elementwise_fma(mk2(hfb[jj].z, hfb[jj].w), v2(wc[jj].w), a);
      }
      a = dpp_red2_32(a);  // lane31: n(half0), lane63: n(half1)
      if (l31 == 31) {
        const int n_ = nbase + 2 * i + half;
        z0[rowe * N_ + n_] = a.x;
        z0[(rowe + 8) * N_ + n_] = a.y;
      }
#pragma unroll
      for (int jj = 0; jj < 4; ++jj) wc[jj] = wn[jj];
    }
  }
}

// ---------------- np_scan: sequential sigmoid scan ----------------
__global__ void __launch_bounds__(512, 1)
np_scan(const float* __restrict__ b_add, float* __restrict__ ws) {
  __shared__ float Wl[T_][T_];   // 64 KB
  __shared__ float ul[T_][64];   // 32 KB
  __shared__ float zx[16][64];   // 4 KB
  const int b = blockIdx.x >> 3, nc = blockIdx.x & 7;
  const int wave = threadIdx.x >> 6, lane = threadIdx.x & 63;
  float* z0 = ws + Z0_OFF;
  const float* Wb = ws + WS_OFF + b * T_ * T_;

#pragma unroll
  for (int i = 0; i < 8; ++i) {
    const int r2 = wave * 16 + i * 2;
    load_lds16(&Wb[r2 * T_ + 4 * lane], &Wl[r2][0]);
  }

  const int ta = 2 * wave, tb2 = 2 * wave + 1;
  const int ncol = nc * 64 + lane;
  const float ban = b_add[ncol];

  float za = z0[(ta * B_ + b) * N_ + ncol] + ban;
  float zb = z0[(tb2 * B_ + b) * N_ + ncol] + ban;
  __syncthreads();  // W staged

  for (int j = 0; j < 8; ++j) {
    const int t0 = j * 16;
    float zna = 0.f, znb = 0.f;
    if (j < 7) {
      zna = z0[((t0 + 16 + ta) * B_ + b) * N_ + ncol] + ban;
      znb = z0[((t0 + 16 + tb2) * B_ + b) * N_ + ncol] + ban;
    }
    float ha0 = 0.f, ha1 = 0.f, hb0 = 0.f, hb1 = 0.f;
#pragma unroll 2
    for (int s4 = 0; s4 < t0; s4 += 4) {
      const float4 wa = *(const float4*)&Wl[t0 + ta][s4];
      const float4 wb = *(const float4*)&Wl[t0 + tb2][s4];
      const float u0 = ul[s4 + 0][lane], u1 = ul[s4 + 1][lane];
      const float u2 = ul[s4 + 2][lane], u3 = ul[s4 + 3][lane];
      ha0 = __builtin_fmaf(wa.x, u0, ha0);
      ha1 = __builtin_fmaf(wa.y, u1, ha1);
      ha0 = __builtin_fmaf(wa.z, u2, ha0);
      ha1 = __builtin_fmaf(wa.w, u3, ha1);
      hb0 = __builtin_fmaf(wb.x, u0, hb0);
      hb1 = __builtin_fmaf(wb.y, u1, hb1);
      hb0 = __builtin_fmaf(wb.z, u2, hb0);
      hb1 = __builtin_fmaf(wb.w, u3, hb1);
    }
    zx[ta][lane] = za + (ha0 + ha1);
    zx[tb2][lane] = zb + (hb0 + hb1);
    __syncthreads();
    if (wave == 0) {
      float z[16], uv[16];
#pragma unroll
      for (int i = 0; i < 16; ++i) z[i] = zx[i][lane];
#pragma unroll
      for (int i = 0; i < 16; ++i) {
        const float u = sigmoid_f(z[i]);
        uv[i] = u;
        z0[((t0 + i) * B_ + b) * N_ + ncol] = u;  // in-place u
#pragma unroll
        for (int tt = i + 1; tt < 16; ++tt)
          z[tt] = __builtin_fmaf(u, Wl[t0 + tt][t0 + i], z[tt]);
      }
#pragma unroll
      for (int i = 0; i < 16; ++i) ul[t0 + i][lane] = uv[i];
    }
    __syncthreads();
    za = zna;
    zb = znb;
  }
}

// ---------------- np_final ----------------
__global__ void __launch_bounds__(512)
np_final(const float* __restrict__ ws, const float* __restrict__ w_final,
         const float* __restrict__ b_final, float* __restrict__ out) {
  const int wave = threadIdx.x >> 6, lane = threadIdx.x & 63;
  const int tb = blockIdx.x * 8 + wave;
  const float* u = ws + Z0_OFF + tb * N_ + lane * 8;
  const float4 a = *(const float4*)u, c = *(const float4*)(u + 4);
  const float4 wa = *(const float4*)&w_final[lane * 8];
  const float4 wc = *(const float4*)&w_final[lane * 8 + 4];
  float d = a.x * wa.x + a.y * wa.y + a.z * wa.z + a.w * wa.w +
            c.x * wc.x + c.y * wc.y + c.z * wc.z + c.w * wc.w;
  d = dpp_wave_sum(d);
  if (lane == 0) out[tb] = sigmoid_f(d + b_final[0]);
}

// ================= fallback path (R5) =================

__global__ void __launch_bounds__(512, 2)
fb_part1(const float* __restrict__ x, const float* __restrict__ w_mult,
         const float* __restrict__ b_mult, const float* __restrict__ p_lm,
         const float* __restrict__ p_em, float* __restrict__ ws) {
  const int g = blockIdx.x & 7, sub = blockIdx.x >> 3;
  const int wave = threadIdx.x >> 6, lane = threadIdx.x & 63;
  const int n0 = (sub * 8 + wave) * 2;
  __shared__ float xs[2][CH][D_];
  const float lam = sigmoid_f(p_lm[0]);
  const float eta = p_em[0];
  const v2f lam2 = v2(lam), klam2 = v2(1.f - lam);
  v2f wm[2][2], Bm[2][2];
  float bm[2];
#pragma unroll
  for (int r = 0; r < 2; ++r) {
    bm[r] = b_mult[n0 + r];
#pragma unroll
    for (int c = 0; c < 2; ++c) {
      wm[r][c] = *(const v2f*)&w_mult[(n0 + r) * D_ + c * 128 + 2 * lane];
      Bm[r][c] = v2(1.f);
    }
  }
  auto issue_stage = [&](int c) {
#pragma unroll
    for (int k = 0; k < 2; ++k) {
      const int row = k * 8 + wave;
      load_lds16(&x[((c * CH + row) * B_ + g) * D_ + 4 * lane],
                 &xs[c & 1][row][0]);
    }
  };
  issue_stage(0);
  __syncthreads();
  v2f xv[2][2];
  auto ldx = [&](int buf, int cb, int tl) {
    xv[buf][0] = *(const v2f*)&xs[cb][tl][2 * lane];
    xv[buf][1] = *(const v2f*)&xs[cb][tl][128 + 2 * lane];
  };
  for (int c = 0; c < NC; ++c) {
    if (c + 1 < NC) issue_stage(c + 1);
    const int cb = c & 1;
    ldx(0, cb, 0);
#pragma unroll
    for (int tl = 0; tl < CH; ++tl) {
      const int buf = tl & 1;
      if (tl + 1 < CH) ldx(buf ^ 1, cb, tl + 1);
      float hmv[2];
#pragma unroll
      for (int r = 0; r < 2; ++r) {
        v2f a = wm[r][0] * xv[buf][0] * Bm[r][0];
        a = __builtin_elementwise_fma(wm[r][1] * xv[buf][1], Bm[r][1], a);
        const float z = dpp_wave_sum(a.x + a.y) + bm[r];
        const float hm = tanh_f(z);
        hmv[r] = hm;
        const v2f c2 = v2(eta * hm);
#pragma unroll
        for (int cc = 0; cc < 2; ++cc) {
          v2f inner = __builtin_elementwise_fma(c2, xv[buf][cc], klam2);
          Bm[r][cc] = __builtin_elementwise_fma(lam2, Bm[r][cc], inner);
        }
      }
      if (lane == 0) {
        v2f hv2;
        hv2.x = hmv[0];
        hv2.y = hmv[1];
        *(v2f*)(ws + ((c * CH + tl) * B_ + g) * N_ + n0) = hv2;
      }
    }
    __syncthreads();
  }
}

__global__ void __launch_bounds__(512, 2)
fb_part2(const float* __restrict__ w_add, const float* __restrict__ b_add,
         const float* __restrict__ w_final, const float* __restrict__ p_la,
         const float* __restrict__ p_ea, float* __restrict__ ws) {
  const int g = blockIdx.x & 7, sub = blockIdx.x >> 3;
  const int wave = threadIdx.x >> 6, lane = threadIdx.x & 63;
  const int n0 = (sub * 8 + wave) * 2;
  __shared__ float hs[2][CH][N_];
  const float lam = sigmoid_f(p_la[0]);
  const float eta = p_ea[0];
  const v2f lam2 = v2(lam);
  const float klam = 1.f - lam;
  v2f Sa[2][4], wb[2][4];
  float ba[2], wf[2];
#pragma unroll
  for (int r = 0; r < 2; ++r) {
    ba[r] = b_add[n0 + r];
    wf[r] = w_final[n0 + r];
#pragma unroll
    for (int c = 0; c < 4; ++c) {
      const v2f wa = *(const v2f*)&w_add[(n0 + r) * N_ + c * 128 + 2 * lane];
      Sa[r][c] = wa;
      wb[r][c] = wa * klam;
    }
  }
  const float* hsrc = ws;
  float* part = ws + HOFF;
  auto issue_stage = [&](int c) {
#pragma unroll
    for (int k = 0; k < 2; ++k) {
      const int row = k * 8 + wave;
#pragma unroll
      for (int jj = 0; jj < 2; ++jj)
        load_lds16(&hsrc[((c * CH + row) * B_ + g) * N_ + jj * 256 + 4 * lane],
                   &hs[c & 1][row][jj * 256]);
    }
  };
  issue_stage(0);
  __syncthreads();
  v2f hv[2][4];
  auto ldh = [&](int buf, int cb, int tl) {
#pragma unroll
    for (int cc = 0; cc < 4; ++cc)
      hv[buf][cc] = *(const v2f*)&hs[cb][tl][cc * 128 + 2 * lane];
  };
  for (int c = 0; c < NC; ++c) {
    if (c + 1 < NC) issue_stage(c + 1);
    const int cb = c & 1;
    ldh(0, cb, 0);
#pragma unroll
    for (int tl = 0; tl < CH; ++tl) {
      const int buf = tl & 1;
      if (tl + 1 < CH) ldh(buf ^ 1, cb, tl + 1);
      float py = 0.f;
#pragma unroll
      for (int r = 0; r < 2; ++r) {
        v2f a0 = Sa[r][0] * hv[buf][0];
        v2f a1 = Sa[r][1] * hv[buf][1];
        a0 = __builtin_elementwise_fma(Sa[r][2], hv[buf][2], a0);
        a1 = __builtin_elementwise_fma(Sa[r][3], hv[buf][3], a1);
        const v2f a = a0 + a1;
        const float z = dpp_wave_sum(a.x + a.y) + ba[r];
        const float ha = sigmoid_f(z);
        const v2f c2 = v2(eta * ha);
#pragma unroll
        for (int cc = 0; cc < 4; ++cc) {
          v2f inner = __builtin_elementwise_fma(c2, hv[buf][cc], wb[r][cc]);
          Sa[r][cc] = __builtin_elementwise_fma(lam2, Sa[r][cc], inner);
        }
        py = __builtin_fmaf(wf[r], ha, py);
      }
      if (lane == 0)
        part[((c * CH + tl) * B_ + g) * 256 + sub * 8 + wave] = py;
    }
    __syncthreads();
  }
}

__global__ void __launch_bounds__(512)
fb_final(const float* __restrict__ ws, const float* __restrict__ b_final,
         float* __restrict__ out) {
  const int wave = threadIdx.x >> 6, lane = threadIdx.x & 63;
  const int tb = blockIdx.x * 8 + wave;
  const float4 v = *(const float4*)(ws + HOFF + tb * 256 + lane * 4);
  const float s = dpp_wave_sum((v.x + v.y) + (v.z + v.w));
  if (lane == 0) out[tb] = sigmoid_f(s + b_final[0]);
}

// ================= launch =================

extern "C" void kernel_launch(void* const* d_in, const int* in_sizes, int n_in,
                              void* d_out, int out_size, void* d_ws,
                              size_t ws_size, hipStream_t stream) {
  const float* x       = (const float*)d_in[0];
  const float* w_mult  = (const float*)d_in[1];
  const float* b_mult  = (const float*)d_in[2];
  const float* w_add   = (const float*)d_in[3];
  const float* b_add   = (const float*)d_in[4];
  const float* w_final = (const float*)d_in[5];
  const float* b_final = (const float*)d_in[6];
  const float* p_lm    = (const float*)d_in[7];
  const float* p_la    = (const float*)d_in[8];
  const float* p_em    = (const float*)d_in[9];
  const float* p_ea    = (const float*)d_in[10];
  float* out = (float*)d_out;
  float* ws  = (float*)d_ws;

  if (ws_size >= WS_NEED) {
    hipLaunchKernelGGL(np_part1, dim3(256), dim3(512), 0, stream,
                       x, w_mult, b_mult, p_lm, p_em, ws);
    hipLaunchKernelGGL(np_mid, dim3(1088), dim3(512), 0, stream,
                       w_add, p_la, p_ea, ws);
    hipLaunchKernelGGL(np_scan, dim3(64), dim3(512), 0, stream, b_add, ws);
    hipLaunchKernelGGL(np_final, dim3(128), dim3(512), 0, stream,
                       ws, w_final, b_final, out);
  } else {
    hipLaunchKernelGGL(fb_part1, dim3(256), dim3(512), 0, stream,
                       x, w_mult, b_mult, p_lm, p_em, ws);
    hipLaunchKernelGGL(fb_part2, dim3(256), dim3(512), 0, stream,
                       w_add, b_add, w_final, p_la, p_ea, ws);
    hipLaunchKernelGGL(fb_final, dim3(128), dim3(512), 0, stream,
                       ws, b_final, out);
  }
}

// Round 11
// 85.488 us; speedup vs baseline: 1.1975x; 1.0348x over previous
//
#include <hip/hip_runtime.h>
#include <cstdint>

// HebbFF T=128,B=8,N=512,D=256,O=1. Gram-matrix reformulation:
//   z(t) = w_add@h_m(t) + b_add + sum_{s<t} W[t][s] u(s),  u = sigmoid(z)
//   W[t][s] = eta_a * lam_a^(t-1-s) * (h_m(s).h_m(t))
// R11: base GEMM gets a 16-pr M-tile: 256 blocks = 8 n-groups x 32 pr-groups.
//   Per thread: 4 n's w rows in regs (reused 16 pr -> w L2 traffic 512->32MB),
//   h streamed per pr (8 coalesced float4, 1-ahead dbuf), dpp_red2_32 reduce,
//   packed float4 z0 stores. No LDS in base path. Gram balanced (R10).
// ws (floats): hp@0 (524288) | z0/u@524288 (524288) | W@1048576 (131072).
// Fallback to R5 path if ws too small.

#define T_ 128
#define B_ 8
#define N_ 512
#define D_ 256
#define HP_OFF 0
#define Z0_OFF 524288
#define WS_OFF 1048576
#define WS_NEED ((size_t)(1048576 + 131072) * 4)
#define HOFF (T_ * B_ * N_)   // fallback layout
#define CH 16
#define NC (T_ / CH)

typedef float v2f __attribute__((ext_vector_type(2)));

__device__ __forceinline__ v2f v2(float s) { v2f r; r.x = s; r.y = s; return r; }
__device__ __forceinline__ v2f mk2(float a, float b) { v2f r; r.x = a; r.y = b; return r; }

__device__ __forceinline__ void load_lds16(const float* g, float* l) {
  __builtin_amdgcn_global_load_lds(
      (const __attribute__((address_space(1))) uint32_t*)(const void*)g,
      (__attribute__((address_space(3))) uint32_t*)(void*)l, 16, 0, 0);
}

#define DPP1(v, ctrl)                                                          \
  v += __int_as_float(                                                         \
      __builtin_amdgcn_update_dpp(0, __float_as_int(v), ctrl, 0xf, 0xf, true))

__device__ __forceinline__ float dpp_red(float v) {
  DPP1(v, 0x111); DPP1(v, 0x112); DPP1(v, 0x114); DPP1(v, 0x118);
  DPP1(v, 0x142); DPP1(v, 0x143);
  return v;
}
__device__ __forceinline__ v2f dpp_red2(v2f v) {
  float a = v.x, b = v.y;
  DPP1(a, 0x111); DPP1(b, 0x111); DPP1(a, 0x112); DPP1(b, 0x112);
  DPP1(a, 0x114); DPP1(b, 0x114); DPP1(a, 0x118); DPP1(b, 0x118);
  DPP1(a, 0x142); DPP1(b, 0x142); DPP1(a, 0x143); DPP1(b, 0x143);
  v.x = a; v.y = b;
  return v;
}
// 32-lane sum: lane31 = sum(0..31), lane63 = sum(32..63)
__device__ __forceinline__ float dpp_red1_32(float v) {
  DPP1(v, 0x111); DPP1(v, 0x112); DPP1(v, 0x114); DPP1(v, 0x118);
  DPP1(v, 0x142);
  return v;
}
__device__ __forceinline__ v2f dpp_red2_32(v2f v) {
  float a = v.x, b = v.y;
  DPP1(a, 0x111); DPP1(b, 0x111); DPP1(a, 0x112); DPP1(b, 0x112);
  DPP1(a, 0x114); DPP1(b, 0x114); DPP1(a, 0x118); DPP1(b, 0x118);
  DPP1(a, 0x142); DPP1(b, 0x142);
  v.x = a; v.y = b;
  return v;
}
__device__ __forceinline__ float dpp_wave_sum(float v) {
  v = dpp_red(v);
  return __int_as_float(__builtin_amdgcn_readlane(__float_as_int(v), 63));
}
__device__ __forceinline__ float sigmoid_f(float z) {
  return __builtin_amdgcn_rcpf(1.f + __expf(-z));
}
__device__ __forceinline__ float tanh_f(float z) {
  return 1.f - 2.f * __builtin_amdgcn_rcpf(1.f + __expf(2.f * z));
}

// ---------------- np_part1: h_mult / A_mult chain (32-lane split) ----------
__global__ void __launch_bounds__(512, 1)
np_part1(const float* __restrict__ x, const float* __restrict__ w_mult,
         const float* __restrict__ b_mult, const float* __restrict__ p_lm,
         const float* __restrict__ p_em, float* __restrict__ ws) {
  const int g = blockIdx.x & 7, sub = blockIdx.x >> 3;
  const int wave = threadIdx.x >> 6, lane = threadIdx.x & 63;
  const int l31 = lane & 31, half = lane >> 5;
  const int n0 = (sub * 8 + wave) * 2;
  const int n = n0 + half;

  __shared__ float xs[T_][D_];  // 128 KB: ALL x rows for batch g
#pragma unroll
  for (int i = 0; i < 16; ++i) {
    const int r = wave * 16 + i;
    load_lds16(&x[(r * B_ + g) * D_ + 4 * lane], &xs[r][0]);
  }

  const float lam = sigmoid_f(p_lm[0]);
  const float eta = p_em[0];
  const v2f lam2 = v2(lam), klam2 = v2(1.f - lam);

  v2f wm[4], Bm[4];
#pragma unroll
  for (int c = 0; c < 4; ++c) {
    wm[c] = *(const v2f*)&w_mult[n * D_ + 64 * c + 2 * l31];
    Bm[c] = v2(1.f);
  }
  const float bm = b_mult[n];
  __syncthreads();  // x staged (drains vmcnt)

  float* hp = ws + HP_OFF;
  v2f xv[4][4];  // 4-slot ring, 3-ahead prefetch
#define LDX(slot, t)                                                           \
  {                                                                            \
    _Pragma("unroll") for (int c = 0; c < 4; ++c)                              \
        xv[slot][c] = *(const v2f*)&xs[t][64 * c + 2 * l31];                   \
  }
  LDX(0, 0) LDX(1, 1) LDX(2, 2)

  float ph = 0.f;
  for (int t4 = 0; t4 < T_; t4 += 4) {
#pragma unroll
    for (int j = 0; j < 4; ++j) {
      const int t = t4 + j;
      if (t + 3 < T_) LDX((j + 3) & 3, t + 3)
      v2f wx = wm[0] * xv[j][0];
      v2f a = wx * Bm[0];
#pragma unroll
      for (int c = 1; c < 4; ++c) {
        wx = wm[c] * xv[j][c];
        a = __builtin_elementwise_fma(wx, Bm[c], a);
      }
      float s = dpp_red1_32(a.x + a.y);
      const float zr0 =
          __int_as_float(__builtin_amdgcn_readlane(__float_as_int(s), 31));
      const float zr1 =
          __int_as_float(__builtin_amdgcn_readlane(__float_as_int(s), 63));
      const float zz = (half ? zr1 : zr0) + bm;
      const float hm = tanh_f(zz);
      const v2f c2 = v2(eta * hm);
#pragma unroll
      for (int c = 0; c < 4; ++c) {
        v2f inner = __builtin_elementwise_fma(c2, xv[j][c], klam2);
        Bm[c] = __builtin_elementwise_fma(lam2, Bm[c], inner);
      }
      if (j & 1) {
        if (l31 == 31)
          *(v2f*)(hp + (size_t)((t >> 1) * B_ + g) * (N_ * 2) + n * 2) =
              mk2(ph, hm);
      } else {
        ph = hm;
      }
    }
  }
#undef LDX
}

// ---------------- np_mid: gram (balanced) + base GEMM (16-pr tile) --------
// 320 blocks x 512 thr. [0,64): gram; [64,320): base.
__global__ void __launch_bounds__(512, 2)
np_mid(const float* __restrict__ w_add, const float* __restrict__ p_la,
       const float* __restrict__ p_ea, float* __restrict__ ws) {
  __shared__ float hl[8192];  // 32 KB (gram only)
  const int wave = threadIdx.x >> 6, lane = threadIdx.x & 63;
  const float* hp = ws + HP_OFF;
  float* z0 = ws + Z0_OFF;
  float* Wsc = ws + WS_OFF;

  if (blockIdx.x < 64) {
    // ---- gram: block (b, qq): halves handle q = qq and q = 15-qq ----
    const int b = blockIdx.x & 7, qq = blockIdx.x >> 3;
    const int hlf = wave >> 2, w4 = wave & 3;
    const int q = hlf ? (15 - qq) : qq;
    float* hb = hl + hlf * 4096;
    const float lam = sigmoid_f(p_la[0]);
    const float eta = p_ea[0];
#pragma unroll
    for (int i = 0; i < 4; ++i)
      load_lds16(&hp[((q * 4 + w4) * 8 + b) * 1024 + i * 256 + 4 * lane],
                 &hb[w4 * 1024 + i * 256]);
    __syncthreads();
    v2f hv[4][8];
#pragma unroll
    for (int i = 0; i < 4; ++i)
#pragma unroll
      for (int j = 0; j < 8; ++j)
        hv[i][j] = ((const v2f*)hb)[i * 512 + lane + 64 * j];

    const float l2lam = __log2f(lam);
    const int tlim = q * 8 + 7;
    float wv[8], wvn[8];
    auto loadg = [&](float* dst, int tp) {
      const float* hrow = hp + ((tp >> 1) * 8 + b) * 1024 + (tp & 1);
#pragma unroll
      for (int j = 0; j < 8; ++j) dst[j] = hrow[2 * (lane + 64 * j)];
    };
    if (w4 < tlim) loadg(wv, w4);
    for (int tp = w4; tp < tlim; tp += 4) {
      if (tp + 4 < tlim) loadg(wvn, tp + 4);
#pragma unroll
      for (int i = 0; i < 4; ++i) {
        v2f a = hv[i][0] * v2(wv[0]);
#pragma unroll
        for (int j = 1; j < 8; ++j)
          a = __builtin_elementwise_fma(hv[i][j], v2(wv[j]), a);
        a = dpp_red2(a);
        if (lane == 63) {
          const int te = q * 8 + 2 * i;
          if (tp < te)
            Wsc[(b * T_ + te) * T_ + tp] =
                eta * exp2f(l2lam * (float)(te - 1 - tp)) * a.x;
          if (tp < te + 1)
            Wsc[(b * T_ + te + 1) * T_ + tp] =
                eta * exp2f(l2lam * (float)(te - tp)) * a.y;
        }
      }
#pragma unroll
      for (int j = 0; j < 8; ++j) wv[j] = wvn[j];
    }
  } else {
    // ---- base: block (ng, pg): 64 n x 16 pr; w in regs, h streamed ----
    const int bx = blockIdx.x - 64;
    const int ng = bx >> 5;   // 0..7: n-group of 64
    const int pg = bx & 31;   // 0..31: pr-group of 16
    const int l31 = lane & 31, half = lane >> 5;
    const int nb = ng * 64 + wave * 8 + half * 4;  // this thread's 4 n

    // w regs: wreg[i][jj] = w_add[nb+i][4*l31 + 128*jj .. +3]
    float4 wreg[4][4];
#pragma unroll
    for (int i = 0; i < 4; ++i) {
      const float* wr = w_add + (size_t)(nb + i) * N_ + 4 * l31;
#pragma unroll
      for (int jj = 0; jj < 4; ++jj)
        wreg[i][jj] = *(const float4*)&wr[128 * jj];
    }

    const float* hbase = hp + (size_t)pg * 16 * 1024 + 8 * l31;
    float4 hA[8], hB[8];
    auto loadh = [&](float4* dst, int it) {
      const float* hr = hbase + it * 1024;
#pragma unroll
      for (int jj = 0; jj < 4; ++jj) {
        dst[2 * jj] = *(const float4*)&hr[256 * jj];
        dst[2 * jj + 1] = *(const float4*)&hr[256 * jj + 4];
      }
    };
    auto compute = [&](const float4* hc, int it) {
      const int pr = pg * 16 + it;
      const int rowe = 16 * (pr >> 3) + (pr & 7);
      float ev[4], od[4];
#pragma unroll
      for (int i = 0; i < 4; ++i) {
        v2f a = v2(0.f);
#pragma unroll
        for (int jj = 0; jj < 4; ++jj) {
          const float4 w4 = wreg[i][jj];
          const float4 h0 = hc[2 * jj], h1 = hc[2 * jj + 1];
          a = __builtin_elementwise_fma(mk2(h0.x, h0.y), v2(w4.x), a);
          a = __builtin_elementwise_fma(mk2(h0.z, h0.w), v2(w4.y), a);
          a = __builtin_elementwise_fma(mk2(h1.x, h1.y), v2(w4.z), a);
          a = __builtin_elementwise_fma(mk2(h1.z, h1.w), v2(w4.w), a);
        }
        a = dpp_red2_32(a);  // lane31: half0's n, lane63: half1's n
        ev[i] = a.x;
        od[i] = a.y;
      }
      if (l31 == 31) {
        *(float4*)&z0[rowe * N_ + nb] = make_float4(ev[0], ev[1], ev[2], ev[3]);
        *(float4*)&z0[(rowe + 8) * N_ + nb] =
            make_float4(od[0], od[1], od[2], od[3]);
      }
    };

    loadh(hA, 0);
    for (int it = 0; it < 16; it += 2) {
      loadh(hB, it + 1);
      compute(hA, it);
      if (it + 2 < 16) loadh(hA, it + 2);
      compute(hB, it + 1);
    }
  }
}

// ---------------- np_scan: sequential sigmoid scan ----------------
__global__ void __launch_bounds__(512, 1)
np_scan(const float* __restrict__ b_add, float* __restrict__ ws) {
  __shared__ float Wl[T_][T_];   // 64 KB
  __shared__ float ul[T_][64];   // 32 KB
  __shared__ float zx[16][64];   // 4 KB
  const int b = blockIdx.x >> 3, nc = blockIdx.x & 7;
  const int wave = threadIdx.x >> 6, lane = threadIdx.x & 63;
  float* z0 = ws + Z0_OFF;
  const float* Wb = ws + WS_OFF + b * T_ * T_;

#pragma unroll
  for (int i = 0; i < 8; ++i) {
    const int r2 = wave * 16 + i * 2;
    load_lds16(&Wb[r2 * T_ + 4 * lane], &Wl[r2][0]);
  }

  const int ta = 2 * wave, tb2 = 2 * wave + 1;
  const int ncol = nc * 64 + lane;
  const float ban = b_add[ncol];

  float za = z0[(ta * B_ + b) * N_ + ncol] + ban;
  float zb = z0[(tb2 * B_ + b) * N_ + ncol] + ban;
  __syncthreads();  // W staged

  for (int j = 0; j < 8; ++j) {
    const int t0 = j * 16;
    float zna = 0.f, znb = 0.f;
    if (j < 7) {
      zna = z0[((t0 + 16 + ta) * B_ + b) * N_ + ncol] + ban;
      znb = z0[((t0 + 16 + tb2) * B_ + b) * N_ + ncol] + ban;
    }
    float ha0 = 0.f, ha1 = 0.f, hb0 = 0.f, hb1 = 0.f;
#pragma unroll 2
    for (int s4 = 0; s4 < t0; s4 += 4) {
      const float4 wa = *(const float4*)&Wl[t0 + ta][s4];
      const float4 wb = *(const float4*)&Wl[t0 + tb2][s4];
      const float u0 = ul[s4 + 0][lane], u1 = ul[s4 + 1][lane];
      const float u2 = ul[s4 + 2][lane], u3 = ul[s4 + 3][lane];
      ha0 = __builtin_fmaf(wa.x, u0, ha0);
      ha1 = __builtin_fmaf(wa.y, u1, ha1);
      ha0 = __builtin_fmaf(wa.z, u2, ha0);
      ha1 = __builtin_fmaf(wa.w, u3, ha1);
      hb0 = __builtin_fmaf(wb.x, u0, hb0);
      hb1 = __builtin_fmaf(wb.y, u1, hb1);
      hb0 = __builtin_fmaf(wb.z, u2, hb0);
      hb1 = __builtin_fmaf(wb.w, u3, hb1);
    }
    zx[ta][lane] = za + (ha0 + ha1);
    zx[tb2][lane] = zb + (hb0 + hb1);
    __syncthreads();
    if (wave == 0) {
      float z[16], uv[16];
#pragma unroll
      for (int i = 0; i < 16; ++i) z[i] = zx[i][lane];
#pragma unroll
      for (int i = 0; i < 16; ++i) {
        const float u = sigmoid_f(z[i]);
        uv[i] = u;
        z0[((t0 + i) * B_ + b) * N_ + ncol] = u;  // in-place u
#pragma unroll
        for (int tt = i + 1; tt < 16; ++tt)
          z[tt] = __builtin_fmaf(u, Wl[t0 + tt][t0 + i], z[tt]);
      }
#pragma unroll
      for (int i = 0; i < 16; ++i) ul[t0 + i][lane] = uv[i];
    }
    __syncthreads();
    za = zna;
    zb = znb;
  }
}

// ---------------- np_final ----------------
__global__ void __launch_bounds__(512)
np_final(const float* __restrict__ ws, const float* __restrict__ w_final,
         const float* __restrict__ b_final, float* __restrict__ out) {
  const int wave = threadIdx.x >> 6, lane = threadIdx.x & 63;
  const int tb = blockIdx.x * 8 + wave;
  const float* u = ws + Z0_OFF + tb * N_ + lane * 8;
  const float4 a = *(const float4*)u, c = *(const float4*)(u + 4);
  const float4 wa = *(const float4*)&w_final[lane * 8];
  const float4 wc = *(const float4*)&w_final[lane * 8 + 4];
  float d = a.x * wa.x + a.y * wa.y + a.z * wa.z + a.w * wa.w +
            c.x * wc.x + c.y * wc.y + c.z * wc.z + c.w * wc.w;
  d = dpp_wave_sum(d);
  if (lane == 0) out[tb] = sigmoid_f(d + b_final[0]);
}

// ================= fallback path (R5) =================

__global__ void __launch_bounds__(512, 2)
fb_part1(const float* __restrict__ x, const float* __restrict__ w_mult,
         const float* __restrict__ b_mult, const float* __restrict__ p_lm,
         const float* __restrict__ p_em, float* __restrict__ ws) {
  const int g = blockIdx.x & 7, sub = blockIdx.x >> 3;
  const int wave = threadIdx.x >> 6, lane = threadIdx.x & 63;
  const int n0 = (sub * 8 + wave) * 2;
  __shared__ float xs[2][CH][D_];
  const float lam = sigmoid_f(p_lm[0]);
  const float eta = p_em[0];
  const v2f lam2 = v2(lam), klam2 = v2(1.f - lam);
  v2f wm[2][2], Bm[2][2];
  float bm[2];
#pragma unroll
  for (int r = 0; r < 2; ++r) {
    bm[r] = b_mult[n0 + r];
#pragma unroll
    for (int c = 0; c < 2; ++c) {
      wm[r][c] = *(const v2f*)&w_mult[(n0 + r) * D_ + c * 128 + 2 * lane];
      Bm[r][c] = v2(1.f);
    }
  }
  auto issue_stage = [&](int c) {
#pragma unroll
    for (int k = 0; k < 2; ++k) {
      const int row = k * 8 + wave;
      load_lds16(&x[((c * CH + row) * B_ + g) * D_ + 4 * lane],
                 &xs[c & 1][row][0]);
    }
  };
  issue_stage(0);
  __syncthreads();
  v2f xv[2][2];
  auto ldx = [&](int buf, int cb, int tl) {
    xv[buf][0] = *(const v2f*)&xs[cb][tl][2 * lane];
    xv[buf][1] = *(const v2f*)&xs[cb][tl][128 + 2 * lane];
  };
  for (int c = 0; c < NC; ++c) {
    if (c + 1 < NC) issue_stage(c + 1);
    const int cb = c & 1;
    ldx(0, cb, 0);
#pragma unroll
    for (int tl = 0; tl < CH; ++tl) {
      const int buf = tl & 1;
      if (tl + 1 < CH) ldx(buf ^ 1, cb, tl + 1);
      float hmv[2];
#pragma unroll
      for (int r = 0; r < 2; ++r) {
        v2f a = wm[r][0] * xv[buf][0] * Bm[r][0];
        a = __builtin_elementwise_fma(wm[r][1] * xv[buf][1], Bm[r][1], a);
        const float z = dpp_wave_sum(a.x + a.y) + bm[r];
        const float hm = tanh_f(z);
        hmv[r] = hm;
        const v2f c2 = v2(eta * hm);
#pragma unroll
        for (int cc = 0; cc < 2; ++cc) {
          v2f inner = __builtin_elementwise_fma(c2, xv[buf][cc], klam2);
          Bm[r][cc] = __builtin_elementwise_fma(lam2, Bm[r][cc], inner);
        }
      }
      if (lane == 0) {
        v2f hv2;
        hv2.x = hmv[0];
        hv2.y = hmv[1];
        *(v2f*)(ws + ((c * CH + tl) * B_ + g) * N_ + n0) = hv2;
      }
    }
    __syncthreads();
  }
}

__global__ void __launch_bounds__(512, 2)
fb_part2(const float* __restrict__ w_add, const float* __restrict__ b_add,
         const float* __restrict__ w_final, const float* __restrict__ p_la,
         const float* __restrict__ p_ea, float* __restrict__ ws) {
  const int g = blockIdx.x & 7, sub = blockIdx.x >> 3;
  const int wave = threadIdx.x >> 6, lane = threadIdx.x & 63;
  const int n0 = (sub * 8 + wave) * 2;
  __shared__ float hs[2][CH][N_];
  const float lam = sigmoid_f(p_la[0]);
  const float eta = p_ea[0];
  const v2f lam2 = v2(lam);
  const float klam = 1.f - lam;
  v2f Sa[2][4], wb[2][4];
  float ba[2], wf[2];
#pragma unroll
  for (int r = 0; r < 2; ++r) {
    ba[r] = b_add[n0 + r];
    wf[r] = w_final[n0 + r];
#pragma unroll
    for (int c = 0; c < 4; ++c) {
      const v2f wa = *(const v2f*)&w_add[(n0 + r) * N_ + c * 128 + 2 * lane];
      Sa[r][c] = wa;
      wb[r][c] = wa * klam;
    }
  }
  const float* hsrc = ws;
  float* part = ws + HOFF;
  auto issue_stage = [&](int c) {
#pragma unroll
    for (int k = 0; k < 2; ++k) {
      const int row = k * 8 + wave;
#pragma unroll
      for (int jj = 0; jj < 2; ++jj)
        load_lds16(&hsrc[((c * CH + row) * B_ + g) * N_ + jj * 256 + 4 * lane],
                   &hs[c & 1][row][jj * 256]);
    }
  };
  issue_stage(0);
  __syncthreads();
  v2f hv[2][4];
  auto ldh = [&](int buf, int cb, int tl) {
#pragma unroll
    for (int cc = 0; cc < 4; ++cc)
      hv[buf][cc] = *(const v2f*)&hs[cb][tl][cc * 128 + 2 * lane];
  };
  for (int c = 0; c < NC; ++c) {
    if (c + 1 < NC) issue_stage(c + 1);
    const int cb = c & 1;
    ldh(0, cb, 0);
#pragma unroll
    for (int tl = 0; tl < CH; ++tl) {
      const int buf = tl & 1;
      if (tl + 1 < CH) ldh(buf ^ 1, cb, tl + 1);
      float py = 0.f;
#pragma unroll
      for (int r = 0; r < 2; ++r) {
        v2f a0 = Sa[r][0] * hv[buf][0];
        v2f a1 = Sa[r][1] * hv[buf][1];
        a0 = __builtin_elementwise_fma(Sa[r][2], hv[buf][2], a0);
        a1 = __builtin_elementwise_fma(Sa[r][3], hv[buf][3], a1);
        const v2f a = a0 + a1;
        const float z = dpp_wave_sum(a.x + a.y) + ba[r];
        const float ha = sigmoid_f(z);
        const v2f c2 = v2(eta * ha);
#pragma unroll
        for (int cc = 0; cc < 4; ++cc) {
          v2f inner = __builtin_elementwise_fma(c2, hv[buf][cc], wb[r][cc]);
          Sa[r][cc] = __builtin_elementwise_fma(lam2, Sa[r][cc], inner);
        }
        py = __builtin_fmaf(wf[r], ha, py);
      }
      if (lane == 0)
        part[((c * CH + tl) * B_ + g) * 256 + sub * 8 + wave] = py;
    }
    __syncthreads();
  }
}

__global__ void __launch_bounds__(512)
fb_final(const float* __restrict__ ws, const float* __restrict__ b_final,
         float* __restrict__ out) {
  const int wave = threadIdx.x >> 6, lane = threadIdx.x & 63;
  const int tb = blockIdx.x * 8 + wave;
  const float4 v = *(const float4*)(ws + HOFF + tb * 256 + lane * 4);
  const float s = dpp_wave_sum((v.x + v.y) + (v.z + v.w));
  if (lane == 0) out[tb] = sigmoid_f(s + b_final[0]);
}

// ================= launch =================

extern "C" void kernel_launch(void* const* d_in, const int* in_sizes, int n_in,
                              void* d_out, int out_size, void* d_ws,
                              size_t ws_size, hipStream_t stream) {
  const float* x       = (const float*)d_in[0];
  const float* w_mult  = (const float*)d_in[1];
  const float* b_mult  = (const float*)d_in[2];
  const float* w_add   = (const float*)d_in[3];
  const float* b_add   = (const float*)d_in[4];
  const float* w_final = (const float*)d_in[5];
  const float* b_final = (const float*)d_in[6];
  const float* p_lm    = (const float*)d_in[7];
  const float* p_la    = (const float*)d_in[8];
  const float* p_em    = (const float*)d_in[9];
  const float* p_ea    = (const float*)d_in[10];
  float* out = (float*)d_out;
  float* ws  = (float*)d_ws;

  if (ws_size >= WS_NEED) {
    hipLaunchKernelGGL(np_part1, dim3(256), dim3(512), 0, stream,
                       x, w_mult, b_mult, p_lm, p_em, ws);
    hipLaunchKernelGGL(np_mid, dim3(320), dim3(512), 0, stream,
                       w_add, p_la, p_ea, ws);
    hipLaunchKernelGGL(np_scan, dim3(64), dim3(512), 0, stream, b_add, ws);
    hipLaunchKernelGGL(np_final, dim3(128), dim3(512), 0, stream,
                       ws, w_final, b_final, out);
  } else {
    hipLaunchKernelGGL(fb_part1, dim3(256), dim3(512), 0, stream,
                       x, w_mult, b_mult, p_lm, p_em, ws);
    hipLaunchKernelGGL(fb_part2, dim3(256), dim3(512), 0, stream,
                       w_add, b_add, w_final, p_la, p_ea, ws);
    hipLaunchKernelGGL(fb_final, dim3(128), dim3(512), 0, stream,
                       ws, b_final, out);
  }
}